// Round 6
// baseline (326.386 us; speedup 1.0000x reference)
//
#include <hip/hip_runtime.h>

typedef __attribute__((ext_vector_type(8))) __bf16 bf16x8;
typedef __attribute__((ext_vector_type(4))) __bf16 bf16x4;
typedef __attribute__((ext_vector_type(4))) float f32x4;

#define MFMA16(a,b,c) __builtin_amdgcn_mfma_f32_16x16x32_bf16(a,b,c,0,0,0)

static constexpr int HW = 65536;   // 256*256
static constexpr int WD = 256;
static constexpr int NB = 2;       // batch
static constexpr double INV_N = 1.0 / 1048576.0;   // 8ch*65536px*2cosets
static constexpr float EPSV = 1e-5f;

// workspace layout (bytes)
static constexpr size_t OFF_P1  = 0;                   // 1024 blocks x 32 f32 partials (stats1+skip)
static constexpr size_t OFF_P2  = 131072;              // 1024 blocks x 16 f32 partials (stats2)
static constexpr size_t OFF_A1  = 200704;              // 20480 bf16
static constexpr size_t OFF_A2  = OFF_A1 + 40960;
static constexpr size_t OFF_AS  = OFF_A2 + 40960;      // 4096 bf16 (wskip 64x64)
static constexpr size_t OFF_XT  = OFF_AS + 8192;
static constexpr size_t SZ_T    = (size_t)2 * NB * HW * 64 * 2;  // 32 MiB
static constexpr size_t OFF_H   = OFF_XT + SZ_T;       // s tensor ELIMINATED

// LDS tile: stride 64 (no pad) + XOR chunk swizzle (chunk ^= px&7) -> conflict-free
// b128 reads AND writes at 128B row stride. (proven correct R1/R3/R5)
#define TL8(base, px, c) (*(const bf16x8*)&(base)[(px) * 64 + (((c)) ^ ((((px)) & 7) << 3))])

// ================ K1: weight prep + stats1 partials + skip stats (no s store) + NHWC transpose ================
__global__ __launch_bounds__(256, 4) void K1(
    const float* __restrict__ x0, const float* __restrict__ x1,
    const float* __restrict__ wskip, const float* __restrict__ bskip,
    const float* __restrict__ wc1, const float* __restrict__ wk1,
    const float* __restrict__ wc2, const float* __restrict__ wk2,
    __bf16* __restrict__ xt,
    __bf16* __restrict__ A1, __bf16* __restrict__ A2, __bf16* __restrict__ Ask,
    float* __restrict__ p1) {
  const int bx = blockIdx.x;
  const int t = threadIdx.x;

  if (bx >= 1024) {            // weight-prep blocks
    const int stage = bx - 1024;
    if (stage == 0) {
      for (int idx = t; idx < 64 * 320 + 64 * 64; idx += 256) {
        if (idx < 64 * 320) {
          int o = idx / 320, k = idx - o * 320;
          float v;
          if (k < 64) v = wc1[o * 64 + k];
          else v = wk1[(o * 64 + (k & 63)) * 4 + ((k - 64) >> 6)];
          A1[idx] = (__bf16)v;
        } else {
          int e = idx - 64 * 320;
          Ask[e] = (__bf16)wskip[e];
        }
      }
    } else {
      for (int idx = t; idx < 64 * 320; idx += 256) {
        int o = idx / 320, k = idx - o * 320;
        float v;
        if (k < 64) v = wc2[o * 64 + k];
        else v = wk2[(o * 64 + (k & 63)) * 4 + ((k - 64) >> 6)];
        A2[idx] = (__bf16)v;
      }
    }
    return;
  }

  const int row = bx & 255, b = (bx >> 8) & 1, co = bx >> 9;
  const float* x = co ? x1 : x0;
  __shared__ __attribute__((aligned(16))) __bf16 tile[256 * 64];
  __shared__ float redp[256];
  __shared__ float reds[32];
  const int wv = t >> 6, lane = t & 63;
  const float* xbase = x + (size_t)b * 64 * HW + (size_t)row * WD + t;
  __bf16* xtbase = xt + (((size_t)(co * NB + b) * HW) + (size_t)row * WD + t) * 64;

  float gsum[8], gsq[8];
#pragma unroll
  for (int g = 0; g < 8; ++g) { gsum[g] = 0.f; gsq[g] = 0.f; }
#pragma unroll
  for (int hf = 0; hf < 2; ++hf) {
    float f[32];
#pragma unroll
    for (int k = 0; k < 32; ++k) f[k] = xbase[(size_t)(hf * 32 + k) * HW];
    __builtin_amdgcn_sched_barrier(0);   // pin: all 32 loads issued before any consume
#pragma unroll
    for (int c4 = 0; c4 < 4; ++c4) {
      const int cg = hf * 4 + c4;
      bf16x8 v;
#pragma unroll
      for (int j = 0; j < 8; ++j) {
        float xv = f[c4 * 8 + j];
        v[j] = (__bf16)xv;
        gsum[cg] += xv;
        gsq[cg] = fmaf(xv, xv, gsq[cg]);
      }
      *(bf16x8*)&tile[t * 64 + ((cg ^ (t & 7)) * 8)] = v;
      *(bf16x8*)&xtbase[cg * 8] = v;
    }
  }
#pragma unroll
  for (int g = 0; g < 8; ++g) {
#pragma unroll
    for (int m = 1; m < 16; m <<= 1) {
      gsum[g] += __shfl_xor(gsum[g], m, 64);
      gsq[g]  += __shfl_xor(gsq[g], m, 64);
    }
  }
  {
    const int q0 = lane >> 4;
    if ((lane & 15) == 0) {
#pragma unroll
      for (int g = 0; g < 8; ++g) {
        redp[(wv * 4 + q0) * 16 + g] = gsum[g];
        redp[(wv * 4 + q0) * 16 + 8 + g] = gsq[g];
      }
    }
  }
  __syncthreads();

  // skip GEMM for STATS ONLY (no store)
  const int ln = lane & 15, q = lane >> 4;
  bf16x8 a0, a1;
#pragma unroll
  for (int j = 0; j < 8; ++j) {
    a0[j] = (__bf16)wskip[(wv * 16 + ln) * 64 + q * 8 + j];
    a1[j] = (__bf16)wskip[(wv * 16 + ln) * 64 + 32 + q * 8 + j];
  }
  float bia[4];
#pragma unroll
  for (int r = 0; r < 4; ++r) bia[r] = bskip[wv * 16 + q * 4 + r];

  float ssum = 0.f, ssq = 0.f;
  for (int n = 0; n < 16; ++n) {
    f32x4 acc = {0.f, 0.f, 0.f, 0.f};
    const int px = n * 16 + ln;
    bf16x8 b0 = TL8(tile, px, q * 8);
    bf16x8 b1 = TL8(tile, px, q * 8 + 32);
    acc = MFMA16(a0, b0, acc);
    acc = MFMA16(a1, b1, acc);
#pragma unroll
    for (int r = 0; r < 4; ++r) {
      float v = acc[r] + bia[r];
      ssum += v;
      ssq = fmaf(v, v, ssq);
    }
  }
#pragma unroll
  for (int m = 1; m < 16; m <<= 1) {
    ssum += __shfl_xor(ssum, m, 64);
    ssq  += __shfl_xor(ssq, m, 64);
  }
  if ((lane & 15) == 0) {
    reds[wv * 4 + q] = ssum;
    reds[16 + wv * 4 + q] = ssq;
  }
  __syncthreads();
  if (t < 32) {
    float val;
    if (t < 16) {
      val = 0.f;
#pragma unroll
      for (int k = 0; k < 16; ++k) val += redp[k * 16 + t];
    } else {
      int kind = (t >> 3) & 1, g = t & 7;
      int wvv = g >> 1, qp = g & 1;
      val = reds[kind * 16 + wvv * 4 + qp * 2] + reds[kind * 16 + wvv * 4 + qp * 2 + 1];
    }
    p1[(size_t)((co * 2 + b) * 256 + row) * 32 + t] = val;
  }
}

// ================ K2: prologue -> interleaved staging -> qc_conv1 -> stats2 partials (unchanged R5) ================
__global__ __launch_bounds__(256, 4) void K2(
    const __bf16* __restrict__ xt, const __bf16* __restrict__ A1,
    const float* __restrict__ p1, const float* __restrict__ g1, const float* __restrict__ be1,
    const float* __restrict__ bias1,
    __bf16* __restrict__ h, float* __restrict__ p2) {
  const int blk = ((blockIdx.x & 7) << 6) | (blockIdx.x >> 3);
  const int tx = blk & 15, ty = blk >> 4;
  const int b = blockIdx.y;
  const int y0p = ty * 8, x0p = tx * 16;
  __shared__ __attribute__((aligned(16))) __bf16 tl[2][153 * 64];
  __shared__ float sc[64], sh[64];
  __shared__ float lst[16];
  __shared__ double redn[16];
  const int t = threadIdx.x;

  if (t < 16) lst[t] = 0.f;
  {
    const int col = t >> 4, sub = t & 15;
    double v = 0.0;
    for (int j = sub; j < 512; j += 16) {
      int cc = j >> 8, rr2 = j & 255;
      v += (double)p1[((size_t)(cc * 2 + b) * 256 + rr2) * 32 + col];
    }
    v += __shfl_xor(v, 1, 64);
    v += __shfl_xor(v, 2, 64);
    v += __shfl_xor(v, 4, 64);
    v += __shfl_xor(v, 8, 64);
    if (sub == 0) redn[col] = v;
  }
  __syncthreads();
  if (t < 64) {
    int g = t >> 3;
    double mean = redn[g] * INV_N;
    double var  = redn[8 + g] * INV_N - mean * mean;
    float inv = rsqrtf((float)var + EPSV);
    float s_ = inv * g1[t];
    sc[t] = s_;
    sh[t] = be1[t] - (float)mean * s_;
  }
  __syncthreads();

#pragma unroll
  for (int i = 0; i < 10; ++i) {
    int u = t + i * 256;
    if (u < 2 * 153 * 8) {
      int cs = u / 1224;
      int rr = u - cs * 1224;
      int px = rr >> 3, cg = rr & 7;
      int ly = px / 17, lx = px - ly * 17;
      int gy = y0p + ly - cs, gx = x0p + lx - cs;
      bf16x8 v;
#pragma unroll
      for (int j = 0; j < 8; ++j) v[j] = (__bf16)0.f;
      if ((unsigned)gy < 256u && (unsigned)gx < 256u) {
        bf16x8 raw = *(const bf16x8*)&xt[(((size_t)(cs * NB + b) * WD + gy) * WD + gx) * 64 + cg * 8];
#pragma unroll
        for (int j = 0; j < 8; ++j) {
          float f = fmaf((float)raw[j], sc[cg * 8 + j], sh[cg * 8 + j]);
          v[j] = (__bf16)fmaxf(f, 0.f);
        }
      }
      *(bf16x8*)&tl[cs][px * 64 + ((cg ^ (px & 7)) * 8)] = v;
    }
  }

  const int wv = t >> 6, lane = t & 63, ln = lane & 15, q = lane >> 4;
  const int co = wv & 1, mh = wv >> 1;
  const int q8 = q * 8;
  bf16x8 af[2][10];
#pragma unroll
  for (int m = 0; m < 2; ++m)
#pragma unroll
    for (int kk = 0; kk < 10; ++kk)
      af[m][kk] = *(const bf16x8*)&A1[(mh * 32 + m * 16 + ln) * 320 + kk * 32 + q8];
  __syncthreads();

  f32x4 acc[8][2];
#pragma unroll
  for (int n = 0; n < 8; ++n)
#pragma unroll
    for (int m = 0; m < 2; ++m) acc[n][m] = (f32x4){0.f, 0.f, 0.f, 0.f};

  const __bf16* tc = tl[co];
  const __bf16* to = tl[1 - co];
#pragma unroll
  for (int n = 0; n < 8; ++n) {
    const int cpix = co ? ((n + 1) * 17 + ln + 1) : (n * 17 + ln);
    const int tb = n * 17 + ln;
    bf16x8 bb;
    bb = TL8(tc, cpix, q8);          acc[n][0]=MFMA16(af[0][0],bb,acc[n][0]); acc[n][1]=MFMA16(af[1][0],bb,acc[n][1]);
    bb = TL8(tc, cpix, q8 + 32);     acc[n][0]=MFMA16(af[0][1],bb,acc[n][0]); acc[n][1]=MFMA16(af[1][1],bb,acc[n][1]);
    bb = TL8(to, tb, q8);            acc[n][0]=MFMA16(af[0][2],bb,acc[n][0]); acc[n][1]=MFMA16(af[1][2],bb,acc[n][1]);
    bb = TL8(to, tb, q8 + 32);       acc[n][0]=MFMA16(af[0][3],bb,acc[n][0]); acc[n][1]=MFMA16(af[1][3],bb,acc[n][1]);
    bb = TL8(to, tb + 1, q8);        acc[n][0]=MFMA16(af[0][4],bb,acc[n][0]); acc[n][1]=MFMA16(af[1][4],bb,acc[n][1]);
    bb = TL8(to, tb + 1, q8 + 32);   acc[n][0]=MFMA16(af[0][5],bb,acc[n][0]); acc[n][1]=MFMA16(af[1][5],bb,acc[n][1]);
    bb = TL8(to, tb + 17, q8);       acc[n][0]=MFMA16(af[0][6],bb,acc[n][0]); acc[n][1]=MFMA16(af[1][6],bb,acc[n][1]);
    bb = TL8(to, tb + 17, q8 + 32);  acc[n][0]=MFMA16(af[0][7],bb,acc[n][0]); acc[n][1]=MFMA16(af[1][7],bb,acc[n][1]);
    bb = TL8(to, tb + 18, q8);       acc[n][0]=MFMA16(af[0][8],bb,acc[n][0]); acc[n][1]=MFMA16(af[1][8],bb,acc[n][1]);
    bb = TL8(to, tb + 18, q8 + 32);  acc[n][0]=MFMA16(af[0][9],bb,acc[n][0]); acc[n][1]=MFMA16(af[1][9],bb,acc[n][1]);
  }

  __syncthreads();   // all waves done reading tl — safe to overwrite with h values

  float s2s[2] = {0.f, 0.f}, s2q[2] = {0.f, 0.f};
  float bia[2][4];
#pragma unroll
  for (int m = 0; m < 2; ++m)
#pragma unroll
    for (int r = 0; r < 4; ++r) bia[m][r] = bias1[mh * 32 + m * 16 + q * 4 + r];

#pragma unroll
  for (int n = 0; n < 8; ++n)
#pragma unroll
    for (int m = 0; m < 2; ++m) {
      bf16x4 hv;
#pragma unroll
      for (int r = 0; r < 4; ++r) {
        float v = acc[n][m][r] + bia[m][r];
        s2s[m] += v;
        s2q[m] = fmaf(v, v, s2q[m]);
        hv[r] = (__bf16)v;
      }
      *(bf16x4*)&tl[co][(n * 16 + ln) * 64 + ((mh * 32 + m * 16 + q * 4) ^ ((ln & 7) << 3))] = hv;
    }

#pragma unroll
  for (int m = 0; m < 2; ++m) {
    float a_ = s2s[m], c_ = s2q[m];
#pragma unroll
    for (int mk = 1; mk < 32; mk <<= 1) {
      a_ += __shfl_xor(a_, mk, 64);
      c_ += __shfl_xor(c_, mk, 64);
    }
    if ((lane & 31) == 0) {
      int g = mh * 4 + m * 2 + (q >> 1);
      atomicAdd(&lst[g], a_);
      atomicAdd(&lst[8 + g], c_);
    }
  }
  __syncthreads();

#pragma unroll
  for (int i = 0; i < 8; ++i) {
    int co2 = i >> 2;
    int idx = (i & 3) * 256 + t;
    int px = idx >> 3, chunk = idx & 7;
    int gy = y0p + (px >> 4), gx = x0p + (px & 15);
    bf16x8 vv = *(const bf16x8*)&tl[co2][px * 64 + ((chunk ^ (px & 7)) * 8)];
    *(bf16x8*)&h[(((size_t)(co2 * NB + b) * WD + gy) * WD + gx) * 64 + chunk * 8] = vv;
  }

  if (t < 16) p2[((size_t)b * 512 + blockIdx.x) * 16 + t] = lst[t];
}

// ================ K3: norm2+relu staging + qc_conv2 + RECOMPUTED skip (MFMA from xt) + fp32 out ================
__global__ __launch_bounds__(256, 4) void K3(
    const __bf16* __restrict__ hin, const __bf16* __restrict__ A2,
    const __bf16* __restrict__ xt, const __bf16* __restrict__ Ask,
    const float* __restrict__ p2, const float* __restrict__ p1,
    const float* __restrict__ g2, const float* __restrict__ be2, const float* __restrict__ bias2,
    const float* __restrict__ gsk, const float* __restrict__ besk, const float* __restrict__ bskip,
    float* __restrict__ out) {
  const int blk = ((blockIdx.x & 7) << 6) | (blockIdx.x >> 3);
  const int tx = blk & 15, ty = blk >> 4;
  const int b = blockIdx.y;
  const int y0p = ty * 8, x0p = tx * 16;
  __shared__ __attribute__((aligned(16))) __bf16 tl[2][153 * 64];
  __shared__ float sc2[64], sh2[64], scS[64], shS[64];
  __shared__ double redn[32];
  const int t = threadIdx.x;

  // prologue: stats2 + skip stats finalize
  {
    const int col = t >> 3, sub = t & 7;
    double v = 0.0;
    if (col < 16) {
      for (int j = sub; j < 512; j += 8)
        v += (double)p2[((size_t)b * 512 + j) * 16 + col];
    } else {
      for (int j = sub; j < 512; j += 8) {
        int cc = j >> 8, rr2 = j & 255;
        v += (double)p1[((size_t)(cc * 2 + b) * 256 + rr2) * 32 + col];
      }
    }
    v += __shfl_xor(v, 1, 64);
    v += __shfl_xor(v, 2, 64);
    v += __shfl_xor(v, 4, 64);
    if (sub == 0) redn[col] = v;
  }
  __syncthreads();
  if (t < 128) {
    int half = t >> 6, ch = t & 63, g = ch >> 3;
    if (half == 0) {
      double mean = redn[g] * INV_N;
      double var  = redn[8 + g] * INV_N - mean * mean;
      float inv = rsqrtf((float)var + EPSV);
      float s_ = inv * g2[ch];
      sc2[ch] = s_;
      sh2[ch] = be2[ch] - (float)mean * s_;
    } else {
      double mean = redn[16 + g] * INV_N;
      double var  = redn[24 + g] * INV_N - mean * mean;
      float inv = rsqrtf((float)var + EPSV);
      float s_ = inv * gsk[ch];
      scS[ch] = s_;
      shS[ch] = besk[ch] - (float)mean * s_;
    }
  }
  __syncthreads();

  // staging: interleaved load+norm+relu+swizzled LDS write
#pragma unroll
  for (int i = 0; i < 10; ++i) {
    int u = t + i * 256;
    if (u < 2 * 153 * 8) {
      int cs = u / 1224;
      int rr = u - cs * 1224;
      int px = rr >> 3, cg = rr & 7;
      int ly = px / 17, lx = px - ly * 17;
      int gy = y0p + ly - cs, gx = x0p + lx - cs;
      bf16x8 v;
#pragma unroll
      for (int j = 0; j < 8; ++j) v[j] = (__bf16)0.f;
      if ((unsigned)gy < 256u && (unsigned)gx < 256u) {
        bf16x8 raw = *(const bf16x8*)&hin[(((size_t)(cs * NB + b) * WD + gy) * WD + gx) * 64 + cg * 8];
#pragma unroll
        for (int j = 0; j < 8; ++j) {
          float f = fmaf((float)raw[j], sc2[cg * 8 + j], sh2[cg * 8 + j]);
          v[j] = (__bf16)fmaxf(f, 0.f);
        }
      }
      *(bf16x8*)&tl[cs][px * 64 + ((cg ^ (px & 7)) * 8)] = v;
    }
  }

  // af prefetch before the barrier
  const int wv = t >> 6, lane = t & 63, ln = lane & 15, q = lane >> 4;
  const int co = wv & 1, mh = wv >> 1;
  const int q8 = q * 8;
  bf16x8 af[2][10];
#pragma unroll
  for (int m = 0; m < 2; ++m)
#pragma unroll
    for (int kk = 0; kk < 10; ++kk)
      af[m][kk] = *(const bf16x8*)&A2[(mh * 32 + m * 16 + ln) * 320 + kk * 32 + q8];
  __syncthreads();

  f32x4 acc[8][2];
#pragma unroll
  for (int n = 0; n < 8; ++n)
#pragma unroll
    for (int m = 0; m < 2; ++m) acc[n][m] = (f32x4){0.f, 0.f, 0.f, 0.f};

  const __bf16* tc = tl[co];
  const __bf16* to = tl[1 - co];
#pragma unroll
  for (int n = 0; n < 8; ++n) {
    const int cpix = co ? ((n + 1) * 17 + ln + 1) : (n * 17 + ln);
    const int tb = n * 17 + ln;
    bf16x8 bb;
    bb = TL8(tc, cpix, q8);          acc[n][0]=MFMA16(af[0][0],bb,acc[n][0]); acc[n][1]=MFMA16(af[1][0],bb,acc[n][1]);
    bb = TL8(tc, cpix, q8 + 32);     acc[n][0]=MFMA16(af[0][1],bb,acc[n][0]); acc[n][1]=MFMA16(af[1][1],bb,acc[n][1]);
    bb = TL8(to, tb, q8);            acc[n][0]=MFMA16(af[0][2],bb,acc[n][0]); acc[n][1]=MFMA16(af[1][2],bb,acc[n][1]);
    bb = TL8(to, tb, q8 + 32);       acc[n][0]=MFMA16(af[0][3],bb,acc[n][0]); acc[n][1]=MFMA16(af[1][3],bb,acc[n][1]);
    bb = TL8(to, tb + 1, q8);        acc[n][0]=MFMA16(af[0][4],bb,acc[n][0]); acc[n][1]=MFMA16(af[1][4],bb,acc[n][1]);
    bb = TL8(to, tb + 1, q8 + 32);   acc[n][0]=MFMA16(af[0][5],bb,acc[n][0]); acc[n][1]=MFMA16(af[1][5],bb,acc[n][1]);
    bb = TL8(to, tb + 17, q8);       acc[n][0]=MFMA16(af[0][6],bb,acc[n][0]); acc[n][1]=MFMA16(af[1][6],bb,acc[n][1]);
    bb = TL8(to, tb + 17, q8 + 32);  acc[n][0]=MFMA16(af[0][7],bb,acc[n][0]); acc[n][1]=MFMA16(af[1][7],bb,acc[n][1]);
    bb = TL8(to, tb + 18, q8);       acc[n][0]=MFMA16(af[0][8],bb,acc[n][0]); acc[n][1]=MFMA16(af[1][8],bb,acc[n][1]);
    bb = TL8(to, tb + 18, q8 + 32);  acc[n][0]=MFMA16(af[0][9],bb,acc[n][0]); acc[n][1]=MFMA16(af[1][9],bb,acc[n][1]);
  }

  // skip A-fragments (wskip bf16, same operand pattern as the verified conv MFMA)
  bf16x8 aS[2][2];
#pragma unroll
  for (int m = 0; m < 2; ++m)
#pragma unroll
    for (int hh = 0; hh < 2; ++hh)
      aS[m][hh] = *(const bf16x8*)&Ask[(mh * 32 + m * 16 + ln) * 64 + hh * 32 + q8];

  float bia[2][4], sA[2][4], sBp[2][4];
#pragma unroll
  for (int m = 0; m < 2; ++m)
#pragma unroll
    for (int r = 0; r < 4; ++r) {
      int ch = mh * 32 + m * 16 + q * 4 + r;
      bia[m][r] = bias2[ch];
      sA[m][r] = scS[ch];
      sBp[m][r] = fmaf(scS[ch], bskip[ch], shS[ch]);   // fold bskip into shift
    }

  // epilogue in 2 halves: hoist xt B-frags, recompute skip via MFMA, write out
#pragma unroll
  for (int ng = 0; ng < 2; ++ng) {
    bf16x8 xb[4][2];
#pragma unroll
    for (int nn = 0; nn < 4; ++nn) {
      int gy = y0p + ng * 4 + nn;
#pragma unroll
      for (int hh = 0; hh < 2; ++hh)
        xb[nn][hh] = *(const bf16x8*)&xt[(((size_t)(co * NB + b) * WD + gy) * WD + x0p + ln) * 64 + hh * 32 + q8];
    }
    __builtin_amdgcn_sched_barrier(0);
#pragma unroll
    for (int nn = 0; nn < 4; ++nn) {
      int n = ng * 4 + nn;
      int gy = y0p + n;
#pragma unroll
      for (int m = 0; m < 2; ++m) {
        f32x4 accS = {0.f, 0.f, 0.f, 0.f};
        accS = MFMA16(aS[m][0], xb[nn][0], accS);
        accS = MFMA16(aS[m][1], xb[nn][1], accS);
        int ch0 = mh * 32 + m * 16 + q * 4;
        size_t ob = ((size_t)(co * NB + b) * 64 + ch0) * HW + (size_t)gy * WD + x0p + ln;
#pragma unroll
        for (int r = 0; r < 4; ++r) {
          float v = acc[n][m][r] + bia[m][r] + fmaf(accS[r], sA[m][r], sBp[m][r]);
          out[ob + (size_t)r * HW] = v;
        }
      }
    }
  }
}

extern "C" void kernel_launch(void* const* d_in, const int* in_sizes, int n_in,
                              void* d_out, int out_size, void* d_ws, size_t ws_size,
                              hipStream_t stream) {
  (void)in_sizes; (void)n_in; (void)out_size; (void)ws_size;
  const float* x0    = (const float*)d_in[0];
  const float* x1    = (const float*)d_in[1];
  const float* g1    = (const float*)d_in[2];
  const float* b1    = (const float*)d_in[3];
  const float* w1c   = (const float*)d_in[4];
  const float* w1k   = (const float*)d_in[5];
  const float* bias1 = (const float*)d_in[6];
  const float* g2    = (const float*)d_in[7];
  const float* b2    = (const float*)d_in[8];
  const float* w2c   = (const float*)d_in[9];
  const float* w2k   = (const float*)d_in[10];
  const float* bias2 = (const float*)d_in[11];
  const float* wsk   = (const float*)d_in[12];
  const float* bsk   = (const float*)d_in[13];
  const float* gsk   = (const float*)d_in[14];
  const float* besk  = (const float*)d_in[15];

  char* ws = (char*)d_ws;
  float*  p1 = (float*)(ws + OFF_P1);
  float*  p2 = (float*)(ws + OFF_P2);
  __bf16* A1 = (__bf16*)(ws + OFF_A1);
  __bf16* A2 = (__bf16*)(ws + OFF_A2);
  __bf16* As = (__bf16*)(ws + OFF_AS);
  __bf16* xt = (__bf16*)(ws + OFF_XT);
  __bf16* h  = (__bf16*)(ws + OFF_H);

  K1<<<dim3(1026), 256, 0, stream>>>(x0, x1, wsk, bsk, w1c, w1k, w2c, w2k, xt, A1, A2, As, p1);
  K2<<<dim3(512, 2), 256, 0, stream>>>(xt, A1, p1, g1, b1, bias1, h, p2);
  K3<<<dim3(512, 2), 256, 0, stream>>>(h, A2, xt, As, p2, p1, g2, b2, bias2, gsk, besk, bsk, (float*)d_out);
}

// Round 7
// 295.029 us; speedup vs baseline: 1.1063x; 1.1063x over previous
//
#include <hip/hip_runtime.h>

typedef __attribute__((ext_vector_type(8))) __bf16 bf16x8;
typedef __attribute__((ext_vector_type(4))) __bf16 bf16x4;
typedef __attribute__((ext_vector_type(4))) float f32x4;

#define MFMA16(a,b,c) __builtin_amdgcn_mfma_f32_16x16x32_bf16(a,b,c,0,0,0)

static constexpr int HW = 65536;   // 256*256
static constexpr int WD = 256;
static constexpr int NB = 2;       // batch
static constexpr double INV_N = 1.0 / 1048576.0;   // 8ch*65536px*2cosets
static constexpr float EPSV = 1e-5f;

// workspace layout (bytes) — R0 layout
static constexpr size_t OFF_P1  = 0;                   // 1024 blocks x 32 f32 partials (stats1+skip)
static constexpr size_t OFF_P2  = 131072;              // 1024 blocks x 16 f32 partials (stats2)
static constexpr size_t OFF_A1  = 200704;              // 20480 bf16
static constexpr size_t OFF_A2  = OFF_A1 + 40960;
static constexpr size_t OFF_XT  = OFF_A2 + 40960;
static constexpr size_t SZ_T    = (size_t)2 * NB * HW * 64 * 2;  // 32 MiB
static constexpr size_t OFF_S   = OFF_XT + SZ_T;
static constexpr size_t OFF_H   = OFF_S + SZ_T;

// K1-only LDS tile: stride 64 + XOR chunk swizzle (conflict-free b128 r/w) — from R3
#define TL8(base, px, c) (*(const bf16x8*)&(base)[(px) * 64 + (((c)) ^ ((((px)) & 7) << 3))])

// ================ K1: weight prep + stats1 partials + skip GEMM + NHWC transpose (R3 version) ================
__global__ __launch_bounds__(256, 4) void K1(
    const float* __restrict__ x0, const float* __restrict__ x1,
    const float* __restrict__ wskip, const float* __restrict__ bskip,
    const float* __restrict__ wc1, const float* __restrict__ wk1,
    const float* __restrict__ wc2, const float* __restrict__ wk2,
    __bf16* __restrict__ xt, __bf16* __restrict__ sout,
    __bf16* __restrict__ A1, __bf16* __restrict__ A2, float* __restrict__ p1) {
  const int bx = blockIdx.x;
  const int t = threadIdx.x;

  if (bx >= 1024) {            // weight-prep blocks
    const int stage = bx - 1024;
    const float* wc = stage ? wc2 : wc1;
    const float* wk = stage ? wk2 : wk1;
    __bf16* A = stage ? A2 : A1;
    for (int idx = t; idx < 64 * 320; idx += 256) {
      int o = idx / 320, k = idx - o * 320;
      float v;
      if (k < 64) v = wc[o * 64 + k];
      else v = wk[(o * 64 + (k & 63)) * 4 + ((k - 64) >> 6)];
      A[idx] = (__bf16)v;
    }
    return;
  }

  const int row = bx & 255, b = (bx >> 8) & 1, co = bx >> 9;
  const float* x = co ? x1 : x0;
  __shared__ __attribute__((aligned(16))) __bf16 tile[256 * 64];
  __shared__ float redp[256];
  __shared__ float reds[32];
  const int wv = t >> 6, lane = t & 63;
  const float* xbase = x + (size_t)b * 64 * HW + (size_t)row * WD + t;
  __bf16* xtbase = xt + (((size_t)(co * NB + b) * HW) + (size_t)row * WD + t) * 64;

  float gsum[8], gsq[8];
#pragma unroll
  for (int g = 0; g < 8; ++g) { gsum[g] = 0.f; gsq[g] = 0.f; }
#pragma unroll
  for (int hf = 0; hf < 2; ++hf) {
    float f[32];
#pragma unroll
    for (int k = 0; k < 32; ++k) f[k] = xbase[(size_t)(hf * 32 + k) * HW];
    __builtin_amdgcn_sched_barrier(0);   // pin: all 32 loads issued before any consume
#pragma unroll
    for (int c4 = 0; c4 < 4; ++c4) {
      const int cg = hf * 4 + c4;
      bf16x8 v;
#pragma unroll
      for (int j = 0; j < 8; ++j) {
        float xv = f[c4 * 8 + j];
        v[j] = (__bf16)xv;
        gsum[cg] += xv;
        gsq[cg] = fmaf(xv, xv, gsq[cg]);
      }
      *(bf16x8*)&tile[t * 64 + ((cg ^ (t & 7)) * 8)] = v;
      *(bf16x8*)&xtbase[cg * 8] = v;
    }
  }
#pragma unroll
  for (int g = 0; g < 8; ++g) {
#pragma unroll
    for (int m = 1; m < 16; m <<= 1) {
      gsum[g] += __shfl_xor(gsum[g], m, 64);
      gsq[g]  += __shfl_xor(gsq[g], m, 64);
    }
  }
  {
    const int q0 = lane >> 4;
    if ((lane & 15) == 0) {
#pragma unroll
      for (int g = 0; g < 8; ++g) {
        redp[(wv * 4 + q0) * 16 + g] = gsum[g];
        redp[(wv * 4 + q0) * 16 + 8 + g] = gsq[g];
      }
    }
  }
  __syncthreads();

  const int ln = lane & 15, q = lane >> 4;
  bf16x8 a0, a1;
#pragma unroll
  for (int j = 0; j < 8; ++j) {
    a0[j] = (__bf16)wskip[(wv * 16 + ln) * 64 + q * 8 + j];
    a1[j] = (__bf16)wskip[(wv * 16 + ln) * 64 + 32 + q * 8 + j];
  }
  float bia[4];
#pragma unroll
  for (int r = 0; r < 4; ++r) bia[r] = bskip[wv * 16 + q * 4 + r];

  float ssum = 0.f, ssq = 0.f;
  for (int n = 0; n < 16; ++n) {
    f32x4 acc = {0.f, 0.f, 0.f, 0.f};
    const int px = n * 16 + ln;
    bf16x8 b0 = TL8(tile, px, q * 8);
    bf16x8 b1 = TL8(tile, px, q * 8 + 32);
    acc = MFMA16(a0, b0, acc);
    acc = MFMA16(a1, b1, acc);
    bf16x4 sv;
#pragma unroll
    for (int r = 0; r < 4; ++r) {
      float v = acc[r] + bia[r];
      ssum += v;
      ssq = fmaf(v, v, ssq);
      sv[r] = (__bf16)v;
    }
    size_t sb = ((size_t)(co * NB + b) * 4096 + row * 16 + n) * 1024 + (wv * 4 + q) * 64 + ln * 4;
    *(bf16x4*)&sout[sb] = sv;
  }
#pragma unroll
  for (int m = 1; m < 16; m <<= 1) {
    ssum += __shfl_xor(ssum, m, 64);
    ssq  += __shfl_xor(ssq, m, 64);
  }
  if ((lane & 15) == 0) {
    reds[wv * 4 + q] = ssum;
    reds[16 + wv * 4 + q] = ssq;
  }
  __syncthreads();
  if (t < 32) {
    float val;
    if (t < 16) {
      val = 0.f;
#pragma unroll
      for (int k = 0; k < 16; ++k) val += redp[k * 16 + t];
    } else {
      int kind = (t >> 3) & 1, g = t & 7;
      int wvv = g >> 1, qp = g & 1;
      val = reds[kind * 16 + wvv * 4 + qp * 2] + reds[kind * 16 + wvv * 4 + qp * 2 + 1];
    }
    p1[(size_t)((co * 2 + b) * 256 + row) * 32 + t] = val;
  }
}

// ================ K2: per-block nrm1 reduce + norm1+relu staging + qc_conv1 + stats2 partials (R0 verbatim) ================
__global__ __launch_bounds__(256) void K2(
    const __bf16* __restrict__ xt, const __bf16* __restrict__ A1,
    const float* __restrict__ p1, const float* __restrict__ g1, const float* __restrict__ be1,
    const float* __restrict__ bias1,
    __bf16* __restrict__ h, float* __restrict__ p2) {
  // XCD swizzle: band of 64 consecutive tiles per XCD for halo L2 locality
  const int blk = ((blockIdx.x & 7) << 6) | (blockIdx.x >> 3);
  const int tx = blk & 15, ty = blk >> 4;
  const int b = blockIdx.y;
  const int y0p = ty * 8, x0p = tx * 16;
  __shared__ __attribute__((aligned(16))) __bf16 tl[2][153 * 72];
  __shared__ double redn[16];
  __shared__ float sc[64], sh[64];
  __shared__ float lst[16];
  const int t = threadIdx.x;

  // prologue: reduce p1 stats1 (16 cols x 512 rows for our b) -> nrm1
  {
    const int col = t >> 4, sub = t & 15;    // 16 cols x 16 subs
    double v = 0.0;
    for (int j = sub; j < 512; j += 16) {
      int cc = j >> 8, rr = j & 255;
      v += (double)p1[((size_t)(cc * 2 + b) * 256 + rr) * 32 + col];
    }
    v += __shfl_xor(v, 1, 64);
    v += __shfl_xor(v, 2, 64);
    v += __shfl_xor(v, 4, 64);
    v += __shfl_xor(v, 8, 64);
    if (sub == 0) redn[col] = v;
  }
  if (t < 16) lst[t] = 0.f;
  __syncthreads();
  if (t < 64) {
    int g = t >> 3;
    double mean = redn[g] * INV_N;
    double var  = redn[8 + g] * INV_N - mean * mean;
    float inv = rsqrtf((float)var + EPSV);
    float s_ = inv * g1[t];
    sc[t] = s_;
    sh[t] = be1[t] - (float)mean * s_;
  }
  __syncthreads();

  // staging: fixed 10 predicated iterations
#pragma unroll
  for (int i = 0; i < 10; ++i) {
    int u = t + i * 256;
    if (u < 2 * 153 * 8) {
      int cs = u / 1224;
      int rr = u - cs * 1224;
      int px = rr >> 3, cg = rr & 7;
      int ly = px / 17, lx = px - ly * 17;
      int gy = y0p + ly - cs, gx = x0p + lx - cs;
      bf16x8 v;
#pragma unroll
      for (int j = 0; j < 8; ++j) v[j] = (__bf16)0.f;
      if ((unsigned)gy < 256u && (unsigned)gx < 256u) {
        bf16x8 raw = *(const bf16x8*)&xt[(((size_t)(cs * NB + b) * WD + gy) * WD + gx) * 64 + cg * 8];
#pragma unroll
        for (int j = 0; j < 8; ++j) {
          float f = fmaf((float)raw[j], sc[cg * 8 + j], sh[cg * 8 + j]);
          v[j] = (__bf16)fmaxf(f, 0.f);
        }
      }
      *(bf16x8*)&tl[cs][px * 72 + cg * 8] = v;
    }
  }
  __syncthreads();

  const int wv = t >> 6, lane = t & 63, ln = lane & 15, q = lane >> 4;
  const int co = wv & 1, mh = wv >> 1;
  const int q8 = q * 8;
  bf16x8 af[2][10];
#pragma unroll
  for (int m = 0; m < 2; ++m)
#pragma unroll
    for (int kk = 0; kk < 10; ++kk)
      af[m][kk] = *(const bf16x8*)&A1[(mh * 32 + m * 16 + ln) * 320 + kk * 32 + q8];

  f32x4 acc[8][2];
#pragma unroll
  for (int n = 0; n < 8; ++n)
#pragma unroll
    for (int m = 0; m < 2; ++m) acc[n][m] = (f32x4){0.f, 0.f, 0.f, 0.f};

  const __bf16* tc = tl[co];
  const __bf16* to = tl[1 - co];
#pragma unroll
  for (int n = 0; n < 8; ++n) {
    const int cpix = co ? ((n + 1) * 17 + ln + 1) : (n * 17 + ln);
    const int tb = n * 17 + ln;
    const __bf16* pc = tc + cpix * 72 + q8;
    const __bf16* p0 = to + tb * 72 + q8;
    const __bf16* p1p = to + (tb + 1) * 72 + q8;
    const __bf16* p2p = to + (tb + 17) * 72 + q8;
    const __bf16* p3 = to + (tb + 18) * 72 + q8;
    bf16x8 bb;
    bb = *(const bf16x8*)pc;         acc[n][0]=MFMA16(af[0][0],bb,acc[n][0]); acc[n][1]=MFMA16(af[1][0],bb,acc[n][1]);
    bb = *(const bf16x8*)(pc + 32);  acc[n][0]=MFMA16(af[0][1],bb,acc[n][0]); acc[n][1]=MFMA16(af[1][1],bb,acc[n][1]);
    bb = *(const bf16x8*)p0;         acc[n][0]=MFMA16(af[0][2],bb,acc[n][0]); acc[n][1]=MFMA16(af[1][2],bb,acc[n][1]);
    bb = *(const bf16x8*)(p0 + 32);  acc[n][0]=MFMA16(af[0][3],bb,acc[n][0]); acc[n][1]=MFMA16(af[1][3],bb,acc[n][1]);
    bb = *(const bf16x8*)p1p;        acc[n][0]=MFMA16(af[0][4],bb,acc[n][0]); acc[n][1]=MFMA16(af[1][4],bb,acc[n][1]);
    bb = *(const bf16x8*)(p1p + 32); acc[n][0]=MFMA16(af[0][5],bb,acc[n][0]); acc[n][1]=MFMA16(af[1][5],bb,acc[n][1]);
    bb = *(const bf16x8*)p2p;        acc[n][0]=MFMA16(af[0][6],bb,acc[n][0]); acc[n][1]=MFMA16(af[1][6],bb,acc[n][1]);
    bb = *(const bf16x8*)(p2p + 32); acc[n][0]=MFMA16(af[0][7],bb,acc[n][0]); acc[n][1]=MFMA16(af[1][7],bb,acc[n][1]);
    bb = *(const bf16x8*)p3;         acc[n][0]=MFMA16(af[0][8],bb,acc[n][0]); acc[n][1]=MFMA16(af[1][8],bb,acc[n][1]);
    bb = *(const bf16x8*)(p3 + 32);  acc[n][0]=MFMA16(af[0][9],bb,acc[n][0]); acc[n][1]=MFMA16(af[1][9],bb,acc[n][1]);
  }

  __syncthreads();   // all waves done reading tl — safe to overwrite with h values

  float s2s[2] = {0.f, 0.f}, s2q[2] = {0.f, 0.f};
  float bia[2][4];
#pragma unroll
  for (int m = 0; m < 2; ++m)
#pragma unroll
    for (int r = 0; r < 4; ++r) bia[m][r] = bias1[mh * 32 + m * 16 + q * 4 + r];

#pragma unroll
  for (int n = 0; n < 8; ++n)
#pragma unroll
    for (int m = 0; m < 2; ++m) {
      bf16x4 hv;
#pragma unroll
      for (int r = 0; r < 4; ++r) {
        float v = acc[n][m][r] + bia[m][r];
        s2s[m] += v;
        s2q[m] = fmaf(v, v, s2q[m]);
        hv[r] = (__bf16)v;
      }
      *(bf16x4*)&tl[co][(n * 16 + ln) * 72 + mh * 32 + m * 16 + q * 4] = hv;
    }

#pragma unroll
  for (int m = 0; m < 2; ++m) {
    float a_ = s2s[m], c_ = s2q[m];
#pragma unroll
    for (int mk = 1; mk < 32; mk <<= 1) {
      a_ += __shfl_xor(a_, mk, 64);
      c_ += __shfl_xor(c_, mk, 64);
    }
    if ((lane & 31) == 0) {
      int g = mh * 4 + m * 2 + (q >> 1);
      atomicAdd(&lst[g], a_);
      atomicAdd(&lst[8 + g], c_);
    }
  }
  __syncthreads();

  // coalesced h store (NHWC), 16 B/lane
#pragma unroll
  for (int i = 0; i < 8; ++i) {
    int co2 = i >> 2;
    int idx = (i & 3) * 256 + t;
    int px = idx >> 3, chunk = idx & 7;
    int gy = y0p + (px >> 4), gx = x0p + (px & 15);
    bf16x8 vv = *(const bf16x8*)&tl[co2][px * 72 + chunk * 8];
    *(bf16x8*)&h[(((size_t)(co2 * NB + b) * WD + gy) * WD + gx) * 64 + chunk * 8] = vv;
  }

  if (t < 16) p2[((size_t)b * 512 + blockIdx.x) * 16 + t] = lst[t];
}

// ================ K3: per-block nrm2+nrmS reduce + norm2+relu staging + qc_conv2 + skip + fp32 out (R0 verbatim) ================
__global__ __launch_bounds__(256) void K3(
    const __bf16* __restrict__ hin, const __bf16* __restrict__ A2,
    const float* __restrict__ p2, const float* __restrict__ p1,
    const float* __restrict__ g2, const float* __restrict__ be2, const float* __restrict__ bias2,
    const float* __restrict__ gsk, const float* __restrict__ besk,
    const __bf16* __restrict__ sin_, float* __restrict__ out) {
  const int blk = ((blockIdx.x & 7) << 6) | (blockIdx.x >> 3);
  const int tx = blk & 15, ty = blk >> 4;
  const int b = blockIdx.y;
  const int y0p = ty * 8, x0p = tx * 16;
  __shared__ __attribute__((aligned(16))) __bf16 tl[2][153 * 72];
  __shared__ double redn[32];
  __shared__ float sc2[64], sh2[64], scS[64], shS[64];
  const int t = threadIdx.x;

  // prologue: reduce p2 (nrm2, cols 0-15) and p1 skip cols (nrmS, cols 16-31)
  {
    const int col = t >> 3, sub = t & 7;    // 32 cols x 8 subs
    double v = 0.0;
    if (col < 16) {
      for (int j = sub; j < 512; j += 8)
        v += (double)p2[((size_t)b * 512 + j) * 16 + col];
    } else {
      for (int j = sub; j < 512; j += 8) {
        int cc = j >> 8, rr = j & 255;
        v += (double)p1[((size_t)(cc * 2 + b) * 256 + rr) * 32 + col];
      }
    }
    v += __shfl_xor(v, 1, 64);
    v += __shfl_xor(v, 2, 64);
    v += __shfl_xor(v, 4, 64);
    if (sub == 0) redn[col] = v;
  }
  __syncthreads();
  if (t < 128) {
    int half = t >> 6, ch = t & 63, g = ch >> 3;
    if (half == 0) {
      double mean = redn[g] * INV_N;
      double var  = redn[8 + g] * INV_N - mean * mean;
      float inv = rsqrtf((float)var + EPSV);
      float s_ = inv * g2[ch];
      sc2[ch] = s_;
      sh2[ch] = be2[ch] - (float)mean * s_;
    } else {
      double mean = redn[16 + g] * INV_N;
      double var  = redn[24 + g] * INV_N - mean * mean;
      float inv = rsqrtf((float)var + EPSV);
      float s_ = inv * gsk[ch];
      scS[ch] = s_;
      shS[ch] = besk[ch] - (float)mean * s_;
    }
  }
  __syncthreads();

#pragma unroll
  for (int i = 0; i < 10; ++i) {
    int u = t + i * 256;
    if (u < 2 * 153 * 8) {
      int cs = u / 1224;
      int rr = u - cs * 1224;
      int px = rr >> 3, cg = rr & 7;
      int ly = px / 17, lx = px - ly * 17;
      int gy = y0p + ly - cs, gx = x0p + lx - cs;
      bf16x8 v;
#pragma unroll
      for (int j = 0; j < 8; ++j) v[j] = (__bf16)0.f;
      if ((unsigned)gy < 256u && (unsigned)gx < 256u) {
        bf16x8 raw = *(const bf16x8*)&hin[(((size_t)(cs * NB + b) * WD + gy) * WD + gx) * 64 + cg * 8];
#pragma unroll
        for (int j = 0; j < 8; ++j) {
          float f = fmaf((float)raw[j], sc2[cg * 8 + j], sh2[cg * 8 + j]);
          v[j] = (__bf16)fmaxf(f, 0.f);
        }
      }
      *(bf16x8*)&tl[cs][px * 72 + cg * 8] = v;
    }
  }
  __syncthreads();

  const int wv = t >> 6, lane = t & 63, ln = lane & 15, q = lane >> 4;
  const int co = wv & 1, mh = wv >> 1;
  const int q8 = q * 8;
  bf16x8 af[2][10];
#pragma unroll
  for (int m = 0; m < 2; ++m)
#pragma unroll
    for (int kk = 0; kk < 10; ++kk)
      af[m][kk] = *(const bf16x8*)&A2[(mh * 32 + m * 16 + ln) * 320 + kk * 32 + q8];

  f32x4 acc[8][2];
#pragma unroll
  for (int n = 0; n < 8; ++n)
#pragma unroll
    for (int m = 0; m < 2; ++m) acc[n][m] = (f32x4){0.f, 0.f, 0.f, 0.f};

  const __bf16* tc = tl[co];
  const __bf16* to = tl[1 - co];
#pragma unroll
  for (int n = 0; n < 8; ++n) {
    const int cpix = co ? ((n + 1) * 17 + ln + 1) : (n * 17 + ln);
    const int tb = n * 17 + ln;
    const __bf16* pc = tc + cpix * 72 + q8;
    const __bf16* p0 = to + tb * 72 + q8;
    const __bf16* p1p = to + (tb + 1) * 72 + q8;
    const __bf16* p2p = to + (tb + 17) * 72 + q8;
    const __bf16* p3 = to + (tb + 18) * 72 + q8;
    bf16x8 bb;
    bb = *(const bf16x8*)pc;         acc[n][0]=MFMA16(af[0][0],bb,acc[n][0]); acc[n][1]=MFMA16(af[1][0],bb,acc[n][1]);
    bb = *(const bf16x8*)(pc + 32);  acc[n][0]=MFMA16(af[0][1],bb,acc[n][0]); acc[n][1]=MFMA16(af[1][1],bb,acc[n][1]);
    bb = *(const bf16x8*)p0;         acc[n][0]=MFMA16(af[0][2],bb,acc[n][0]); acc[n][1]=MFMA16(af[1][2],bb,acc[n][1]);
    bb = *(const bf16x8*)(p0 + 32);  acc[n][0]=MFMA16(af[0][3],bb,acc[n][0]); acc[n][1]=MFMA16(af[1][3],bb,acc[n][1]);
    bb = *(const bf16x8*)p1p;        acc[n][0]=MFMA16(af[0][4],bb,acc[n][0]); acc[n][1]=MFMA16(af[1][4],bb,acc[n][1]);
    bb = *(const bf16x8*)(p1p + 32); acc[n][0]=MFMA16(af[0][5],bb,acc[n][0]); acc[n][1]=MFMA16(af[1][5],bb,acc[n][1]);
    bb = *(const bf16x8*)p2p;        acc[n][0]=MFMA16(af[0][6],bb,acc[n][0]); acc[n][1]=MFMA16(af[1][6],bb,acc[n][1]);
    bb = *(const bf16x8*)(p2p + 32); acc[n][0]=MFMA16(af[0][7],bb,acc[n][0]); acc[n][1]=MFMA16(af[1][7],bb,acc[n][1]);
    bb = *(const bf16x8*)p3;         acc[n][0]=MFMA16(af[0][8],bb,acc[n][0]); acc[n][1]=MFMA16(af[1][8],bb,acc[n][1]);
    bb = *(const bf16x8*)(p3 + 32);  acc[n][0]=MFMA16(af[0][9],bb,acc[n][0]); acc[n][1]=MFMA16(af[1][9],bb,acc[n][1]);
  }

  float bia[2][4], sA[2][4], sB[2][4];
#pragma unroll
  for (int m = 0; m < 2; ++m)
#pragma unroll
    for (int r = 0; r < 4; ++r) {
      int ch = mh * 32 + m * 16 + q * 4 + r;
      bia[m][r] = bias2[ch];
      sA[m][r] = scS[ch];
      sB[m][r] = shS[ch];
    }

#pragma unroll
  for (int n = 0; n < 8; ++n) {
    int gy = y0p + n;
#pragma unroll
    for (int m = 0; m < 2; ++m) {
      int ch0 = mh * 32 + m * 16 + q * 4;
      size_t sb = ((size_t)(co * NB + b) * 4096 + gy * 16 + tx) * 1024 + (mh * 8 + m * 4 + q) * 64 + ln * 4;
      bf16x4 sv = *(const bf16x4*)&sin_[sb];
      size_t ob = ((size_t)(co * NB + b) * 64 + ch0) * HW + (size_t)gy * WD + x0p + ln;
#pragma unroll
      for (int r = 0; r < 4; ++r) {
        float v = acc[n][m][r] + bia[m][r] + fmaf((float)sv[r], sA[m][r], sB[m][r]);
        out[ob + (size_t)r * HW] = v;
      }
    }
  }
}

extern "C" void kernel_launch(void* const* d_in, const int* in_sizes, int n_in,
                              void* d_out, int out_size, void* d_ws, size_t ws_size,
                              hipStream_t stream) {
  (void)in_sizes; (void)n_in; (void)out_size; (void)ws_size;
  const float* x0    = (const float*)d_in[0];
  const float* x1    = (const float*)d_in[1];
  const float* g1    = (const float*)d_in[2];
  const float* b1    = (const float*)d_in[3];
  const float* w1c   = (const float*)d_in[4];
  const float* w1k   = (const float*)d_in[5];
  const float* bias1 = (const float*)d_in[6];
  const float* g2    = (const float*)d_in[7];
  const float* b2    = (const float*)d_in[8];
  const float* w2c   = (const float*)d_in[9];
  const float* w2k   = (const float*)d_in[10];
  const float* bias2 = (const float*)d_in[11];
  const float* wsk   = (const float*)d_in[12];
  const float* bsk   = (const float*)d_in[13];
  const float* gsk   = (const float*)d_in[14];
  const float* besk  = (const float*)d_in[15];

  char* ws = (char*)d_ws;
  float*  p1 = (float*)(ws + OFF_P1);
  float*  p2 = (float*)(ws + OFF_P2);
  __bf16* A1 = (__bf16*)(ws + OFF_A1);
  __bf16* A2 = (__bf16*)(ws + OFF_A2);
  __bf16* xt = (__bf16*)(ws + OFF_XT);
  __bf16* s  = (__bf16*)(ws + OFF_S);
  __bf16* h  = (__bf16*)(ws + OFF_H);

  K1<<<dim3(1026), 256, 0, stream>>>(x0, x1, wsk, bsk, w1c, w1k, w2c, w2k, xt, s, A1, A2, p1);
  K2<<<dim3(512, 2), 256, 0, stream>>>(xt, A1, p1, g1, b1, bias1, h, p2);
  K3<<<dim3(512, 2), 256, 0, stream>>>(h, A2, p2, p1, g2, b2, bias2, gsk, besk, s, (float*)d_out);
}

// Round 8
// 272.750 us; speedup vs baseline: 1.1967x; 1.0817x over previous
//
#include <hip/hip_runtime.h>

typedef __attribute__((ext_vector_type(8))) __bf16 bf16x8;
typedef __attribute__((ext_vector_type(4))) __bf16 bf16x4;
typedef __attribute__((ext_vector_type(4))) float f32x4;

#define MFMA16(a,b,c) __builtin_amdgcn_mfma_f32_16x16x32_bf16(a,b,c,0,0,0)

static constexpr int HW = 65536;   // 256*256
static constexpr int WD = 256;
static constexpr int NB = 2;       // batch
static constexpr double INV_N = 1.0 / 1048576.0;   // 8ch*65536px*2cosets
static constexpr float EPSV = 1e-5f;

// workspace layout (bytes)
// p1 TRANSPOSED: [32 cols][1024 rows] f32  (row = (co*2+b)*256 + rowIdx)
// p2 TRANSPOSED: [16 cols][1024 rows] f32  (row = b*512 + blk)
static constexpr size_t OFF_P1  = 0;                   // 131072 B
static constexpr size_t OFF_P2  = 131072;              // 65536 B
static constexpr size_t OFF_A1  = 200704;              // 20480 bf16
static constexpr size_t OFF_A2  = OFF_A1 + 40960;
static constexpr size_t OFF_XT  = OFF_A2 + 40960;
static constexpr size_t SZ_T    = (size_t)2 * NB * HW * 64 * 2;  // 32 MiB
static constexpr size_t OFF_S   = OFF_XT + SZ_T;
static constexpr size_t OFF_H   = OFF_S + SZ_T;

// K1-only LDS tile: stride 64 + XOR chunk swizzle (conflict-free b128 r/w)
#define TL8(base, px, c) (*(const bf16x8*)&(base)[(px) * 64 + (((c)) ^ ((((px)) & 7) << 3))])

// ================ K1: weight prep + stats1 partials + skip GEMM + NHWC transpose ================
__global__ __launch_bounds__(256, 4) void K1(
    const float* __restrict__ x0, const float* __restrict__ x1,
    const float* __restrict__ wskip, const float* __restrict__ bskip,
    const float* __restrict__ wc1, const float* __restrict__ wk1,
    const float* __restrict__ wc2, const float* __restrict__ wk2,
    __bf16* __restrict__ xt, __bf16* __restrict__ sout,
    __bf16* __restrict__ A1, __bf16* __restrict__ A2, float* __restrict__ p1) {
  const int bx = blockIdx.x;
  const int t = threadIdx.x;

  if (bx >= 1024) {            // weight-prep blocks
    const int stage = bx - 1024;
    const float* wc = stage ? wc2 : wc1;
    const float* wk = stage ? wk2 : wk1;
    __bf16* A = stage ? A2 : A1;
    for (int idx = t; idx < 64 * 320; idx += 256) {
      int o = idx / 320, k = idx - o * 320;
      float v;
      if (k < 64) v = wc[o * 64 + k];
      else v = wk[(o * 64 + (k & 63)) * 4 + ((k - 64) >> 6)];
      A[idx] = (__bf16)v;
    }
    return;
  }

  const int row = bx & 255, b = (bx >> 8) & 1, co = bx >> 9;
  const float* x = co ? x1 : x0;
  __shared__ __attribute__((aligned(16))) __bf16 tile[256 * 64];
  __shared__ float redp[256];
  __shared__ float reds[32];
  const int wv = t >> 6, lane = t & 63;
  const float* xbase = x + (size_t)b * 64 * HW + (size_t)row * WD + t;
  __bf16* xtbase = xt + (((size_t)(co * NB + b) * HW) + (size_t)row * WD + t) * 64;

  float gsum[8], gsq[8];
#pragma unroll
  for (int g = 0; g < 8; ++g) { gsum[g] = 0.f; gsq[g] = 0.f; }
#pragma unroll
  for (int hf = 0; hf < 2; ++hf) {
    float f[32];
#pragma unroll
    for (int k = 0; k < 32; ++k) f[k] = xbase[(size_t)(hf * 32 + k) * HW];
    __builtin_amdgcn_sched_barrier(0);   // pin: all 32 loads issued before any consume
#pragma unroll
    for (int c4 = 0; c4 < 4; ++c4) {
      const int cg = hf * 4 + c4;
      bf16x8 v;
#pragma unroll
      for (int j = 0; j < 8; ++j) {
        float xv = f[c4 * 8 + j];
        v[j] = (__bf16)xv;
        gsum[cg] += xv;
        gsq[cg] = fmaf(xv, xv, gsq[cg]);
      }
      *(bf16x8*)&tile[t * 64 + ((cg ^ (t & 7)) * 8)] = v;
      *(bf16x8*)&xtbase[cg * 8] = v;
    }
  }
#pragma unroll
  for (int g = 0; g < 8; ++g) {
#pragma unroll
    for (int m = 1; m < 16; m <<= 1) {
      gsum[g] += __shfl_xor(gsum[g], m, 64);
      gsq[g]  += __shfl_xor(gsq[g], m, 64);
    }
  }
  {
    const int q0 = lane >> 4;
    if ((lane & 15) == 0) {
#pragma unroll
      for (int g = 0; g < 8; ++g) {
        redp[(wv * 4 + q0) * 16 + g] = gsum[g];
        redp[(wv * 4 + q0) * 16 + 8 + g] = gsq[g];
      }
    }
  }
  __syncthreads();

  const int ln = lane & 15, q = lane >> 4;
  bf16x8 a0, a1;
#pragma unroll
  for (int j = 0; j < 8; ++j) {
    a0[j] = (__bf16)wskip[(wv * 16 + ln) * 64 + q * 8 + j];
    a1[j] = (__bf16)wskip[(wv * 16 + ln) * 64 + 32 + q * 8 + j];
  }
  float bia[4];
#pragma unroll
  for (int r = 0; r < 4; ++r) bia[r] = bskip[wv * 16 + q * 4 + r];

  float ssum = 0.f, ssq = 0.f;
  for (int n = 0; n < 16; ++n) {
    f32x4 acc = {0.f, 0.f, 0.f, 0.f};
    const int px = n * 16 + ln;
    bf16x8 b0 = TL8(tile, px, q * 8);
    bf16x8 b1 = TL8(tile, px, q * 8 + 32);
    acc = MFMA16(a0, b0, acc);
    acc = MFMA16(a1, b1, acc);
    bf16x4 sv;
#pragma unroll
    for (int r = 0; r < 4; ++r) {
      float v = acc[r] + bia[r];
      ssum += v;
      ssq = fmaf(v, v, ssq);
      sv[r] = (__bf16)v;
    }
    size_t sb = ((size_t)(co * NB + b) * 4096 + row * 16 + n) * 1024 + (wv * 4 + q) * 64 + ln * 4;
    *(bf16x4*)&sout[sb] = sv;
  }
#pragma unroll
  for (int m = 1; m < 16; m <<= 1) {
    ssum += __shfl_xor(ssum, m, 64);
    ssq  += __shfl_xor(ssq, m, 64);
  }
  if ((lane & 15) == 0) {
    reds[wv * 4 + q] = ssum;
    reds[16 + wv * 4 + q] = ssq;
  }
  __syncthreads();
  if (t < 32) {
    float val;
    if (t < 16) {
      val = 0.f;
#pragma unroll
      for (int k = 0; k < 16; ++k) val += redp[k * 16 + t];
    } else {
      int kind = (t >> 3) & 1, g = t & 7;
      int wvv = g >> 1, qp = g & 1;
      val = reds[kind * 16 + wvv * 4 + qp * 2] + reds[kind * 16 + wvv * 4 + qp * 2 + 1];
    }
    // TRANSPOSED partials store: p1[col][row] -> coalesced prologue reads in K2/K3
    const int bf1 = (co * 2 + b) * 256 + row;
    p1[(size_t)t * 1024 + bf1] = val;
  }
}

// ================ K2: per-block nrm1 reduce (coalesced) + norm1+relu staging + qc_conv1 + stats2 partials ================
__global__ __launch_bounds__(256) void K2(
    const __bf16* __restrict__ xt, const __bf16* __restrict__ A1,
    const float* __restrict__ p1, const float* __restrict__ g1, const float* __restrict__ be1,
    const float* __restrict__ bias1,
    __bf16* __restrict__ h, float* __restrict__ p2) {
  // XCD swizzle: band of 64 consecutive tiles per XCD for halo L2 locality
  const int blk = ((blockIdx.x & 7) << 6) | (blockIdx.x >> 3);
  const int tx = blk & 15, ty = blk >> 4;
  const int b = blockIdx.y;
  const int y0p = ty * 8, x0p = tx * 16;
  __shared__ __attribute__((aligned(16))) __bf16 tl[2][153 * 72];
  __shared__ double redn[16];
  __shared__ float sc[64], sh[64];
  __shared__ float lst[16];
  const int t = threadIdx.x;

  // prologue: reduce p1 stats1 (16 cols x 512 rows for our b) -> nrm1
  // transposed layout: p1[col*1024 + (cc*2+b)*256 + rr] -> lane-consecutive reads
  {
    const int col = t >> 4, sub = t & 15;    // 16 cols x 16 subs
    double v = 0.0;
    for (int j = sub; j < 512; j += 16) {
      int cc = j >> 8, rr = j & 255;
      v += (double)p1[(size_t)col * 1024 + (cc * 2 + b) * 256 + rr];
    }
    v += __shfl_xor(v, 1, 64);
    v += __shfl_xor(v, 2, 64);
    v += __shfl_xor(v, 4, 64);
    v += __shfl_xor(v, 8, 64);
    if (sub == 0) redn[col] = v;
  }
  if (t < 16) lst[t] = 0.f;
  __syncthreads();
  if (t < 64) {
    int g = t >> 3;
    double mean = redn[g] * INV_N;
    double var  = redn[8 + g] * INV_N - mean * mean;
    float inv = rsqrtf((float)var + EPSV);
    float s_ = inv * g1[t];
    sc[t] = s_;
    sh[t] = be1[t] - (float)mean * s_;
  }
  __syncthreads();

  // staging: fixed 10 predicated iterations
#pragma unroll
  for (int i = 0; i < 10; ++i) {
    int u = t + i * 256;
    if (u < 2 * 153 * 8) {
      int cs = u / 1224;
      int rr = u - cs * 1224;
      int px = rr >> 3, cg = rr & 7;
      int ly = px / 17, lx = px - ly * 17;
      int gy = y0p + ly - cs, gx = x0p + lx - cs;
      bf16x8 v;
#pragma unroll
      for (int j = 0; j < 8; ++j) v[j] = (__bf16)0.f;
      if ((unsigned)gy < 256u && (unsigned)gx < 256u) {
        bf16x8 raw = *(const bf16x8*)&xt[(((size_t)(cs * NB + b) * WD + gy) * WD + gx) * 64 + cg * 8];
#pragma unroll
        for (int j = 0; j < 8; ++j) {
          float f = fmaf((float)raw[j], sc[cg * 8 + j], sh[cg * 8 + j]);
          v[j] = (__bf16)fmaxf(f, 0.f);
        }
      }
      *(bf16x8*)&tl[cs][px * 72 + cg * 8] = v;
    }
  }
  __syncthreads();

  const int wv = t >> 6, lane = t & 63, ln = lane & 15, q = lane >> 4;
  const int co = wv & 1, mh = wv >> 1;
  const int q8 = q * 8;
  bf16x8 af[2][10];
#pragma unroll
  for (int m = 0; m < 2; ++m)
#pragma unroll
    for (int kk = 0; kk < 10; ++kk)
      af[m][kk] = *(const bf16x8*)&A1[(mh * 32 + m * 16 + ln) * 320 + kk * 32 + q8];

  f32x4 acc[8][2];
#pragma unroll
  for (int n = 0; n < 8; ++n)
#pragma unroll
    for (int m = 0; m < 2; ++m) acc[n][m] = (f32x4){0.f, 0.f, 0.f, 0.f};

  const __bf16* tc = tl[co];
  const __bf16* to = tl[1 - co];
#pragma unroll
  for (int n = 0; n < 8; ++n) {
    const int cpix = co ? ((n + 1) * 17 + ln + 1) : (n * 17 + ln);
    const int tb = n * 17 + ln;
    const __bf16* pc = tc + cpix * 72 + q8;
    const __bf16* p0 = to + tb * 72 + q8;
    const __bf16* p1p = to + (tb + 1) * 72 + q8;
    const __bf16* p2p = to + (tb + 17) * 72 + q8;
    const __bf16* p3 = to + (tb + 18) * 72 + q8;
    bf16x8 bb;
    bb = *(const bf16x8*)pc;         acc[n][0]=MFMA16(af[0][0],bb,acc[n][0]); acc[n][1]=MFMA16(af[1][0],bb,acc[n][1]);
    bb = *(const bf16x8*)(pc + 32);  acc[n][0]=MFMA16(af[0][1],bb,acc[n][0]); acc[n][1]=MFMA16(af[1][1],bb,acc[n][1]);
    bb = *(const bf16x8*)p0;         acc[n][0]=MFMA16(af[0][2],bb,acc[n][0]); acc[n][1]=MFMA16(af[1][2],bb,acc[n][1]);
    bb = *(const bf16x8*)(p0 + 32);  acc[n][0]=MFMA16(af[0][3],bb,acc[n][0]); acc[n][1]=MFMA16(af[1][3],bb,acc[n][1]);
    bb = *(const bf16x8*)p1p;        acc[n][0]=MFMA16(af[0][4],bb,acc[n][0]); acc[n][1]=MFMA16(af[1][4],bb,acc[n][1]);
    bb = *(const bf16x8*)(p1p + 32); acc[n][0]=MFMA16(af[0][5],bb,acc[n][0]); acc[n][1]=MFMA16(af[1][5],bb,acc[n][1]);
    bb = *(const bf16x8*)p2p;        acc[n][0]=MFMA16(af[0][6],bb,acc[n][0]); acc[n][1]=MFMA16(af[1][6],bb,acc[n][1]);
    bb = *(const bf16x8*)(p2p + 32); acc[n][0]=MFMA16(af[0][7],bb,acc[n][0]); acc[n][1]=MFMA16(af[1][7],bb,acc[n][1]);
    bb = *(const bf16x8*)p3;         acc[n][0]=MFMA16(af[0][8],bb,acc[n][0]); acc[n][1]=MFMA16(af[1][8],bb,acc[n][1]);
    bb = *(const bf16x8*)(p3 + 32);  acc[n][0]=MFMA16(af[0][9],bb,acc[n][0]); acc[n][1]=MFMA16(af[1][9],bb,acc[n][1]);
  }

  __syncthreads();   // all waves done reading tl — safe to overwrite with h values

  float s2s[2] = {0.f, 0.f}, s2q[2] = {0.f, 0.f};
  float bia[2][4];
#pragma unroll
  for (int m = 0; m < 2; ++m)
#pragma unroll
    for (int r = 0; r < 4; ++r) bia[m][r] = bias1[mh * 32 + m * 16 + q * 4 + r];

#pragma unroll
  for (int n = 0; n < 8; ++n)
#pragma unroll
    for (int m = 0; m < 2; ++m) {
      bf16x4 hv;
#pragma unroll
      for (int r = 0; r < 4; ++r) {
        float v = acc[n][m][r] + bia[m][r];
        s2s[m] += v;
        s2q[m] = fmaf(v, v, s2q[m]);
        hv[r] = (__bf16)v;
      }
      *(bf16x4*)&tl[co][(n * 16 + ln) * 72 + mh * 32 + m * 16 + q * 4] = hv;
    }

#pragma unroll
  for (int m = 0; m < 2; ++m) {
    float a_ = s2s[m], c_ = s2q[m];
#pragma unroll
    for (int mk = 1; mk < 32; mk <<= 1) {
      a_ += __shfl_xor(a_, mk, 64);
      c_ += __shfl_xor(c_, mk, 64);
    }
    if ((lane & 31) == 0) {
      int g = mh * 4 + m * 2 + (q >> 1);
      atomicAdd(&lst[g], a_);
      atomicAdd(&lst[8 + g], c_);
    }
  }
  __syncthreads();

  // coalesced h store (NHWC), 16 B/lane
#pragma unroll
  for (int i = 0; i < 8; ++i) {
    int co2 = i >> 2;
    int idx = (i & 3) * 256 + t;
    int px = idx >> 3, chunk = idx & 7;
    int gy = y0p + (px >> 4), gx = x0p + (px & 15);
    bf16x8 vv = *(const bf16x8*)&tl[co2][px * 72 + chunk * 8];
    *(bf16x8*)&h[(((size_t)(co2 * NB + b) * WD + gy) * WD + gx) * 64 + chunk * 8] = vv;
  }

  // TRANSPOSED partials store: p2[col][b*512 + blk]
  if (t < 16) p2[(size_t)t * 1024 + b * 512 + blockIdx.x] = lst[t];
}

// ================ K3: per-block nrm2+nrmS reduce (coalesced) + norm2+relu staging + qc_conv2 + skip + fp32 out ================
__global__ __launch_bounds__(256) void K3(
    const __bf16* __restrict__ hin, const __bf16* __restrict__ A2,
    const float* __restrict__ p2, const float* __restrict__ p1,
    const float* __restrict__ g2, const float* __restrict__ be2, const float* __restrict__ bias2,
    const float* __restrict__ gsk, const float* __restrict__ besk,
    const __bf16* __restrict__ sin_, float* __restrict__ out) {
  const int blk = ((blockIdx.x & 7) << 6) | (blockIdx.x >> 3);
  const int tx = blk & 15, ty = blk >> 4;
  const int b = blockIdx.y;
  const int y0p = ty * 8, x0p = tx * 16;
  __shared__ __attribute__((aligned(16))) __bf16 tl[2][153 * 72];
  __shared__ double redn[32];
  __shared__ float sc2[64], sh2[64], scS[64], shS[64];
  const int t = threadIdx.x;

  // prologue: reduce p2 (nrm2, cols 0-15) and p1 skip cols (nrmS, cols 16-31)
  // transposed layouts -> lane-consecutive reads
  {
    const int col = t >> 3, sub = t & 7;    // 32 cols x 8 subs
    double v = 0.0;
    if (col < 16) {
      for (int j = sub; j < 512; j += 8)
        v += (double)p2[(size_t)col * 1024 + b * 512 + j];
    } else {
      for (int j = sub; j < 512; j += 8) {
        int cc = j >> 8, rr = j & 255;
        v += (double)p1[(size_t)col * 1024 + (cc * 2 + b) * 256 + rr];
      }
    }
    v += __shfl_xor(v, 1, 64);
    v += __shfl_xor(v, 2, 64);
    v += __shfl_xor(v, 4, 64);
    if (sub == 0) redn[col] = v;
  }
  __syncthreads();
  if (t < 128) {
    int half = t >> 6, ch = t & 63, g = ch >> 3;
    if (half == 0) {
      double mean = redn[g] * INV_N;
      double var  = redn[8 + g] * INV_N - mean * mean;
      float inv = rsqrtf((float)var + EPSV);
      float s_ = inv * g2[ch];
      sc2[ch] = s_;
      sh2[ch] = be2[ch] - (float)mean * s_;
    } else {
      double mean = redn[16 + g] * INV_N;
      double var  = redn[24 + g] * INV_N - mean * mean;
      float inv = rsqrtf((float)var + EPSV);
      float s_ = inv * gsk[ch];
      scS[ch] = s_;
      shS[ch] = besk[ch] - (float)mean * s_;
    }
  }
  __syncthreads();

#pragma unroll
  for (int i = 0; i < 10; ++i) {
    int u = t + i * 256;
    if (u < 2 * 153 * 8) {
      int cs = u / 1224;
      int rr = u - cs * 1224;
      int px = rr >> 3, cg = rr & 7;
      int ly = px / 17, lx = px - ly * 17;
      int gy = y0p + ly - cs, gx = x0p + lx - cs;
      bf16x8 v;
#pragma unroll
      for (int j = 0; j < 8; ++j) v[j] = (__bf16)0.f;
      if ((unsigned)gy < 256u && (unsigned)gx < 256u) {
        bf16x8 raw = *(const bf16x8*)&hin[(((size_t)(cs * NB + b) * WD + gy) * WD + gx) * 64 + cg * 8];
#pragma unroll
        for (int j = 0; j < 8; ++j) {
          float f = fmaf((float)raw[j], sc2[cg * 8 + j], sh2[cg * 8 + j]);
          v[j] = (__bf16)fmaxf(f, 0.f);
        }
      }
      *(bf16x8*)&tl[cs][px * 72 + cg * 8] = v;
    }
  }
  __syncthreads();

  const int wv = t >> 6, lane = t & 63, ln = lane & 15, q = lane >> 4;
  const int co = wv & 1, mh = wv >> 1;
  const int q8 = q * 8;
  bf16x8 af[2][10];
#pragma unroll
  for (int m = 0; m < 2; ++m)
#pragma unroll
    for (int kk = 0; kk < 10; ++kk)
      af[m][kk] = *(const bf16x8*)&A2[(mh * 32 + m * 16 + ln) * 320 + kk * 32 + q8];

  f32x4 acc[8][2];
#pragma unroll
  for (int n = 0; n < 8; ++n)
#pragma unroll
    for (int m = 0; m < 2; ++m) acc[n][m] = (f32x4){0.f, 0.f, 0.f, 0.f};

  const __bf16* tc = tl[co];
  const __bf16* to = tl[1 - co];
#pragma unroll
  for (int n = 0; n < 8; ++n) {
    const int cpix = co ? ((n + 1) * 17 + ln + 1) : (n * 17 + ln);
    const int tb = n * 17 + ln;
    const __bf16* pc = tc + cpix * 72 + q8;
    const __bf16* p0 = to + tb * 72 + q8;
    const __bf16* p1p = to + (tb + 1) * 72 + q8;
    const __bf16* p2p = to + (tb + 17) * 72 + q8;
    const __bf16* p3 = to + (tb + 18) * 72 + q8;
    bf16x8 bb;
    bb = *(const bf16x8*)pc;         acc[n][0]=MFMA16(af[0][0],bb,acc[n][0]); acc[n][1]=MFMA16(af[1][0],bb,acc[n][1]);
    bb = *(const bf16x8*)(pc + 32);  acc[n][0]=MFMA16(af[0][1],bb,acc[n][0]); acc[n][1]=MFMA16(af[1][1],bb,acc[n][1]);
    bb = *(const bf16x8*)p0;         acc[n][0]=MFMA16(af[0][2],bb,acc[n][0]); acc[n][1]=MFMA16(af[1][2],bb,acc[n][1]);
    bb = *(const bf16x8*)(p0 + 32);  acc[n][0]=MFMA16(af[0][3],bb,acc[n][0]); acc[n][1]=MFMA16(af[1][3],bb,acc[n][1]);
    bb = *(const bf16x8*)p1p;        acc[n][0]=MFMA16(af[0][4],bb,acc[n][0]); acc[n][1]=MFMA16(af[1][4],bb,acc[n][1]);
    bb = *(const bf16x8*)(p1p + 32); acc[n][0]=MFMA16(af[0][5],bb,acc[n][0]); acc[n][1]=MFMA16(af[1][5],bb,acc[n][1]);
    bb = *(const bf16x8*)p2p;        acc[n][0]=MFMA16(af[0][6],bb,acc[n][0]); acc[n][1]=MFMA16(af[1][6],bb,acc[n][1]);
    bb = *(const bf16x8*)(p2p + 32); acc[n][0]=MFMA16(af[0][7],bb,acc[n][0]); acc[n][1]=MFMA16(af[1][7],bb,acc[n][1]);
    bb = *(const bf16x8*)p3;         acc[n][0]=MFMA16(af[0][8],bb,acc[n][0]); acc[n][1]=MFMA16(af[1][8],bb,acc[n][1]);
    bb = *(const bf16x8*)(p3 + 32);  acc[n][0]=MFMA16(af[0][9],bb,acc[n][0]); acc[n][1]=MFMA16(af[1][9],bb,acc[n][1]);
  }

  float bia[2][4], sA[2][4], sB[2][4];
#pragma unroll
  for (int m = 0; m < 2; ++m)
#pragma unroll
    for (int r = 0; r < 4; ++r) {
      int ch = mh * 32 + m * 16 + q * 4 + r;
      bia[m][r] = bias2[ch];
      sA[m][r] = scS[ch];
      sB[m][r] = shS[ch];
    }

#pragma unroll
  for (int n = 0; n < 8; ++n) {
    int gy = y0p + n;
#pragma unroll
    for (int m = 0; m < 2; ++m) {
      int ch0 = mh * 32 + m * 16 + q * 4;
      size_t sb = ((size_t)(co * NB + b) * 4096 + gy * 16 + tx) * 1024 + (mh * 8 + m * 4 + q) * 64 + ln * 4;
      bf16x4 sv = *(const bf16x4*)&sin_[sb];
      size_t ob = ((size_t)(co * NB + b) * 64 + ch0) * HW + (size_t)gy * WD + x0p + ln;
#pragma unroll
      for (int r = 0; r < 4; ++r) {
        float v = acc[n][m][r] + bia[m][r] + fmaf((float)sv[r], sA[m][r], sB[m][r]);
        out[ob + (size_t)r * HW] = v;
      }
    }
  }
}

extern "C" void kernel_launch(void* const* d_in, const int* in_sizes, int n_in,
                              void* d_out, int out_size, void* d_ws, size_t ws_size,
                              hipStream_t stream) {
  (void)in_sizes; (void)n_in; (void)out_size; (void)ws_size;
  const float* x0    = (const float*)d_in[0];
  const float* x1    = (const float*)d_in[1];
  const float* g1    = (const float*)d_in[2];
  const float* b1    = (const float*)d_in[3];
  const float* w1c   = (const float*)d_in[4];
  const float* w1k   = (const float*)d_in[5];
  const float* bias1 = (const float*)d_in[6];
  const float* g2    = (const float*)d_in[7];
  const float* b2    = (const float*)d_in[8];
  const float* w2c   = (const float*)d_in[9];
  const float* w2k   = (const float*)d_in[10];
  const float* bias2 = (const float*)d_in[11];
  const float* wsk   = (const float*)d_in[12];
  const float* bsk   = (const float*)d_in[13];
  const float* gsk   = (const float*)d_in[14];
  const float* besk  = (const float*)d_in[15];

  char* ws = (char*)d_ws;
  float*  p1 = (float*)(ws + OFF_P1);
  float*  p2 = (float*)(ws + OFF_P2);
  __bf16* A1 = (__bf16*)(ws + OFF_A1);
  __bf16* A2 = (__bf16*)(ws + OFF_A2);
  __bf16* xt = (__bf16*)(ws + OFF_XT);
  __bf16* s  = (__bf16*)(ws + OFF_S);
  __bf16* h  = (__bf16*)(ws + OFF_H);

  K1<<<dim3(1026), 256, 0, stream>>>(x0, x1, wsk, bsk, w1c, w1k, w2c, w2k, xt, s, A1, A2, p1);
  K2<<<dim3(512, 2), 256, 0, stream>>>(xt, A1, p1, g1, b1, bias1, h, p2);
  K3<<<dim3(512, 2), 256, 0, stream>>>(h, A2, p2, p1, g2, b2, bias2, gsk, besk, s, (float*)d_out);
}

// Round 9
// 267.637 us; speedup vs baseline: 1.2195x; 1.0191x over previous
//
#include <hip/hip_runtime.h>

typedef __attribute__((ext_vector_type(8))) __bf16 bf16x8;
typedef __attribute__((ext_vector_type(4))) __bf16 bf16x4;
typedef __attribute__((ext_vector_type(4))) float f32x4;

#define MFMA16(a,b,c) __builtin_amdgcn_mfma_f32_16x16x32_bf16(a,b,c,0,0,0)

static constexpr int HW = 65536;   // 256*256
static constexpr int WD = 256;
static constexpr int NB = 2;       // batch
static constexpr double INV_N = 1.0 / 1048576.0;   // 8ch*65536px*2cosets
static constexpr float EPSV = 1e-5f;

// workspace layout (bytes)
// p1 TRANSPOSED: [32 cols][1024 rows] f32  (row = (co*2+b)*256 + rowIdx)
// p2 TRANSPOSED: [16 cols][1024 rows] f32  (row = b*512 + blk)
static constexpr size_t OFF_P1  = 0;                   // 131072 B
static constexpr size_t OFF_P2  = 131072;              // 65536 B
static constexpr size_t OFF_A1  = 200704;              // 20480 bf16
static constexpr size_t OFF_A2  = OFF_A1 + 40960;
static constexpr size_t OFF_XT  = OFF_A2 + 40960;
static constexpr size_t SZ_T    = (size_t)2 * NB * HW * 64 * 2;  // 32 MiB
static constexpr size_t OFF_S   = OFF_XT + SZ_T;
static constexpr size_t OFF_H   = OFF_S + SZ_T;

// K1-only LDS tile: stride 64 + XOR chunk swizzle (conflict-free b128 r/w)
#define TL8(base, px, c) (*(const bf16x8*)&(base)[(px) * 64 + (((c)) ^ ((((px)) & 7) << 3))])

// ================ K1: weight prep + stats1 partials + skip GEMM + COALESCED NHWC transpose ================
__global__ __launch_bounds__(256, 4) void K1(
    const float* __restrict__ x0, const float* __restrict__ x1,
    const float* __restrict__ wskip, const float* __restrict__ bskip,
    const float* __restrict__ wc1, const float* __restrict__ wk1,
    const float* __restrict__ wc2, const float* __restrict__ wk2,
    __bf16* __restrict__ xt, __bf16* __restrict__ sout,
    __bf16* __restrict__ A1, __bf16* __restrict__ A2, float* __restrict__ p1) {
  const int bx = blockIdx.x;
  const int t = threadIdx.x;

  if (bx >= 1024) {            // weight-prep blocks
    const int stage = bx - 1024;
    const float* wc = stage ? wc2 : wc1;
    const float* wk = stage ? wk2 : wk1;
    __bf16* A = stage ? A2 : A1;
    for (int idx = t; idx < 64 * 320; idx += 256) {
      int o = idx / 320, k = idx - o * 320;
      float v;
      if (k < 64) v = wc[o * 64 + k];
      else v = wk[(o * 64 + (k & 63)) * 4 + ((k - 64) >> 6)];
      A[idx] = (__bf16)v;
    }
    return;
  }

  const int row = bx & 255, b = (bx >> 8) & 1, co = bx >> 9;
  const float* x = co ? x1 : x0;
  __shared__ __attribute__((aligned(16))) __bf16 tile[256 * 64];
  __shared__ float redp[256];
  __shared__ float reds[32];
  const int wv = t >> 6, lane = t & 63;
  const float* xbase = x + (size_t)b * 64 * HW + (size_t)row * WD + t;

  float gsum[8], gsq[8];
#pragma unroll
  for (int g = 0; g < 8; ++g) { gsum[g] = 0.f; gsq[g] = 0.f; }
#pragma unroll
  for (int hf = 0; hf < 2; ++hf) {
    float f[32];
#pragma unroll
    for (int k = 0; k < 32; ++k) f[k] = xbase[(size_t)(hf * 32 + k) * HW];
    __builtin_amdgcn_sched_barrier(0);   // pin: all 32 loads issued before any consume
#pragma unroll
    for (int c4 = 0; c4 < 4; ++c4) {
      const int cg = hf * 4 + c4;
      bf16x8 v;
#pragma unroll
      for (int j = 0; j < 8; ++j) {
        float xv = f[c4 * 8 + j];
        v[j] = (__bf16)xv;
        gsum[cg] += xv;
        gsq[cg] = fmaf(xv, xv, gsq[cg]);
      }
      *(bf16x8*)&tile[t * 64 + ((cg ^ (t & 7)) * 8)] = v;
      // xt store moved to the coalesced pass below (was: 16B @ 128B lane-stride here)
    }
  }
#pragma unroll
  for (int g = 0; g < 8; ++g) {
#pragma unroll
    for (int m = 1; m < 16; m <<= 1) {
      gsum[g] += __shfl_xor(gsum[g], m, 64);
      gsq[g]  += __shfl_xor(gsq[g], m, 64);
    }
  }
  {
    const int q0 = lane >> 4;
    if ((lane & 15) == 0) {
#pragma unroll
      for (int g = 0; g < 8; ++g) {
        redp[(wv * 4 + q0) * 16 + g] = gsum[g];
        redp[(wv * 4 + q0) * 16 + 8 + g] = gsq[g];
      }
    }
  }
  __syncthreads();

  const int ln = lane & 15, q = lane >> 4;
  bf16x8 a0, a1;
#pragma unroll
  for (int j = 0; j < 8; ++j) {
    a0[j] = (__bf16)wskip[(wv * 16 + ln) * 64 + q * 8 + j];
    a1[j] = (__bf16)wskip[(wv * 16 + ln) * 64 + 32 + q * 8 + j];
  }
  float bia[4];
#pragma unroll
  for (int r = 0; r < 4; ++r) bia[r] = bskip[wv * 16 + q * 4 + r];

  float ssum = 0.f, ssq = 0.f;
  for (int n = 0; n < 16; ++n) {
    f32x4 acc = {0.f, 0.f, 0.f, 0.f};
    const int px = n * 16 + ln;
    bf16x8 b0 = TL8(tile, px, q * 8);
    bf16x8 b1 = TL8(tile, px, q * 8 + 32);
    acc = MFMA16(a0, b0, acc);
    acc = MFMA16(a1, b1, acc);
    bf16x4 sv;
#pragma unroll
    for (int r = 0; r < 4; ++r) {
      float v = acc[r] + bia[r];
      ssum += v;
      ssq = fmaf(v, v, ssq);
      sv[r] = (__bf16)v;
    }
    size_t sb = ((size_t)(co * NB + b) * 4096 + row * 16 + n) * 1024 + (wv * 4 + q) * 64 + ln * 4;
    *(bf16x4*)&sout[sb] = sv;
  }

  // coalesced xt store from LDS tile (16 B/lane contiguous; same pattern as K2's h-store)
  {
    const size_t xtrow = (((size_t)(co * NB + b) * HW) + (size_t)row * WD) * 64;
#pragma unroll
    for (int i = 0; i < 8; ++i) {
      int u = i * 256 + t;
      int px = u >> 3, chunk = u & 7;
      bf16x8 vv = *(const bf16x8*)&tile[px * 64 + ((chunk ^ (px & 7)) * 8)];
      *(bf16x8*)&xt[xtrow + (size_t)u * 8] = vv;
    }
  }

#pragma unroll
  for (int m = 1; m < 16; m <<= 1) {
    ssum += __shfl_xor(ssum, m, 64);
    ssq  += __shfl_xor(ssq, m, 64);
  }
  if ((lane & 15) == 0) {
    reds[wv * 4 + q] = ssum;
    reds[16 + wv * 4 + q] = ssq;
  }
  __syncthreads();
  if (t < 32) {
    float val;
    if (t < 16) {
      val = 0.f;
#pragma unroll
      for (int k = 0; k < 16; ++k) val += redp[k * 16 + t];
    } else {
      int kind = (t >> 3) & 1, g = t & 7;
      int wvv = g >> 1, qp = g & 1;
      val = reds[kind * 16 + wvv * 4 + qp * 2] + reds[kind * 16 + wvv * 4 + qp * 2 + 1];
    }
    // TRANSPOSED partials store: p1[col][row] -> coalesced prologue reads in K2/K3
    const int bf1 = (co * 2 + b) * 256 + row;
    p1[(size_t)t * 1024 + bf1] = val;
  }
}

// ================ K2: per-block nrm1 reduce (coalesced) + norm1+relu staging + qc_conv1 + stats2 partials ================
__global__ __launch_bounds__(256) void K2(
    const __bf16* __restrict__ xt, const __bf16* __restrict__ A1,
    const float* __restrict__ p1, const float* __restrict__ g1, const float* __restrict__ be1,
    const float* __restrict__ bias1,
    __bf16* __restrict__ h, float* __restrict__ p2) {
  // XCD swizzle: band of 64 consecutive tiles per XCD for halo L2 locality
  const int blk = ((blockIdx.x & 7) << 6) | (blockIdx.x >> 3);
  const int tx = blk & 15, ty = blk >> 4;
  const int b = blockIdx.y;
  const int y0p = ty * 8, x0p = tx * 16;
  __shared__ __attribute__((aligned(16))) __bf16 tl[2][153 * 72];
  __shared__ double redn[16];
  __shared__ float sc[64], sh[64];
  __shared__ float lst[16];
  const int t = threadIdx.x;

  // prologue: reduce p1 stats1 (16 cols x 512 rows for our b) -> nrm1
  {
    const int col = t >> 4, sub = t & 15;    // 16 cols x 16 subs
    double v = 0.0;
    for (int j = sub; j < 512; j += 16) {
      int cc = j >> 8, rr = j & 255;
      v += (double)p1[(size_t)col * 1024 + (cc * 2 + b) * 256 + rr];
    }
    v += __shfl_xor(v, 1, 64);
    v += __shfl_xor(v, 2, 64);
    v += __shfl_xor(v, 4, 64);
    v += __shfl_xor(v, 8, 64);
    if (sub == 0) redn[col] = v;
  }
  if (t < 16) lst[t] = 0.f;
  __syncthreads();
  if (t < 64) {
    int g = t >> 3;
    double mean = redn[g] * INV_N;
    double var  = redn[8 + g] * INV_N - mean * mean;
    float inv = rsqrtf((float)var + EPSV);
    float s_ = inv * g1[t];
    sc[t] = s_;
    sh[t] = be1[t] - (float)mean * s_;
  }
  __syncthreads();

  // staging: fixed 10 predicated iterations
#pragma unroll
  for (int i = 0; i < 10; ++i) {
    int u = t + i * 256;
    if (u < 2 * 153 * 8) {
      int cs = u / 1224;
      int rr = u - cs * 1224;
      int px = rr >> 3, cg = rr & 7;
      int ly = px / 17, lx = px - ly * 17;
      int gy = y0p + ly - cs, gx = x0p + lx - cs;
      bf16x8 v;
#pragma unroll
      for (int j = 0; j < 8; ++j) v[j] = (__bf16)0.f;
      if ((unsigned)gy < 256u && (unsigned)gx < 256u) {
        bf16x8 raw = *(const bf16x8*)&xt[(((size_t)(cs * NB + b) * WD + gy) * WD + gx) * 64 + cg * 8];
#pragma unroll
        for (int j = 0; j < 8; ++j) {
          float f = fmaf((float)raw[j], sc[cg * 8 + j], sh[cg * 8 + j]);
          v[j] = (__bf16)fmaxf(f, 0.f);
        }
      }
      *(bf16x8*)&tl[cs][px * 72 + cg * 8] = v;
    }
  }
  __syncthreads();

  const int wv = t >> 6, lane = t & 63, ln = lane & 15, q = lane >> 4;
  const int co = wv & 1, mh = wv >> 1;
  const int q8 = q * 8;
  bf16x8 af[2][10];
#pragma unroll
  for (int m = 0; m < 2; ++m)
#pragma unroll
    for (int kk = 0; kk < 10; ++kk)
      af[m][kk] = *(const bf16x8*)&A1[(mh * 32 + m * 16 + ln) * 320 + kk * 32 + q8];

  f32x4 acc[8][2];
#pragma unroll
  for (int n = 0; n < 8; ++n)
#pragma unroll
    for (int m = 0; m < 2; ++m) acc[n][m] = (f32x4){0.f, 0.f, 0.f, 0.f};

  const __bf16* tc = tl[co];
  const __bf16* to = tl[1 - co];
#pragma unroll
  for (int n = 0; n < 8; ++n) {
    const int cpix = co ? ((n + 1) * 17 + ln + 1) : (n * 17 + ln);
    const int tb = n * 17 + ln;
    const __bf16* pc = tc + cpix * 72 + q8;
    const __bf16* p0 = to + tb * 72 + q8;
    const __bf16* p1p = to + (tb + 1) * 72 + q8;
    const __bf16* p2p = to + (tb + 17) * 72 + q8;
    const __bf16* p3 = to + (tb + 18) * 72 + q8;
    bf16x8 bb;
    bb = *(const bf16x8*)pc;         acc[n][0]=MFMA16(af[0][0],bb,acc[n][0]); acc[n][1]=MFMA16(af[1][0],bb,acc[n][1]);
    bb = *(const bf16x8*)(pc + 32);  acc[n][0]=MFMA16(af[0][1],bb,acc[n][0]); acc[n][1]=MFMA16(af[1][1],bb,acc[n][1]);
    bb = *(const bf16x8*)p0;         acc[n][0]=MFMA16(af[0][2],bb,acc[n][0]); acc[n][1]=MFMA16(af[1][2],bb,acc[n][1]);
    bb = *(const bf16x8*)(p0 + 32);  acc[n][0]=MFMA16(af[0][3],bb,acc[n][0]); acc[n][1]=MFMA16(af[1][3],bb,acc[n][1]);
    bb = *(const bf16x8*)p1p;        acc[n][0]=MFMA16(af[0][4],bb,acc[n][0]); acc[n][1]=MFMA16(af[1][4],bb,acc[n][1]);
    bb = *(const bf16x8*)(p1p + 32); acc[n][0]=MFMA16(af[0][5],bb,acc[n][0]); acc[n][1]=MFMA16(af[1][5],bb,acc[n][1]);
    bb = *(const bf16x8*)p2p;        acc[n][0]=MFMA16(af[0][6],bb,acc[n][0]); acc[n][1]=MFMA16(af[1][6],bb,acc[n][1]);
    bb = *(const bf16x8*)(p2p + 32); acc[n][0]=MFMA16(af[0][7],bb,acc[n][0]); acc[n][1]=MFMA16(af[1][7],bb,acc[n][1]);
    bb = *(const bf16x8*)p3;         acc[n][0]=MFMA16(af[0][8],bb,acc[n][0]); acc[n][1]=MFMA16(af[1][8],bb,acc[n][1]);
    bb = *(const bf16x8*)(p3 + 32);  acc[n][0]=MFMA16(af[0][9],bb,acc[n][0]); acc[n][1]=MFMA16(af[1][9],bb,acc[n][1]);
  }

  __syncthreads();   // all waves done reading tl — safe to overwrite with h values

  float s2s[2] = {0.f, 0.f}, s2q[2] = {0.f, 0.f};
  float bia[2][4];
#pragma unroll
  for (int m = 0; m < 2; ++m)
#pragma unroll
    for (int r = 0; r < 4; ++r) bia[m][r] = bias1[mh * 32 + m * 16 + q * 4 + r];

#pragma unroll
  for (int n = 0; n < 8; ++n)
#pragma unroll
    for (int m = 0; m < 2; ++m) {
      bf16x4 hv;
#pragma unroll
      for (int r = 0; r < 4; ++r) {
        float v = acc[n][m][r] + bia[m][r];
        s2s[m] += v;
        s2q[m] = fmaf(v, v, s2q[m]);
        hv[r] = (__bf16)v;
      }
      *(bf16x4*)&tl[co][(n * 16 + ln) * 72 + mh * 32 + m * 16 + q * 4] = hv;
    }

#pragma unroll
  for (int m = 0; m < 2; ++m) {
    float a_ = s2s[m], c_ = s2q[m];
#pragma unroll
    for (int mk = 1; mk < 32; mk <<= 1) {
      a_ += __shfl_xor(a_, mk, 64);
      c_ += __shfl_xor(c_, mk, 64);
    }
    if ((lane & 31) == 0) {
      int g = mh * 4 + m * 2 + (q >> 1);
      atomicAdd(&lst[g], a_);
      atomicAdd(&lst[8 + g], c_);
    }
  }
  __syncthreads();

  // coalesced h store (NHWC), 16 B/lane
#pragma unroll
  for (int i = 0; i < 8; ++i) {
    int co2 = i >> 2;
    int idx = (i & 3) * 256 + t;
    int px = idx >> 3, chunk = idx & 7;
    int gy = y0p + (px >> 4), gx = x0p + (px & 15);
    bf16x8 vv = *(const bf16x8*)&tl[co2][px * 72 + chunk * 8];
    *(bf16x8*)&h[(((size_t)(co2 * NB + b) * WD + gy) * WD + gx) * 64 + chunk * 8] = vv;
  }

  // TRANSPOSED partials store: p2[col][b*512 + blk]
  if (t < 16) p2[(size_t)t * 1024 + b * 512 + blockIdx.x] = lst[t];
}

// ================ K3: per-block nrm2+nrmS reduce (coalesced) + norm2+relu staging + qc_conv2 + skip + fp32 out ================
__global__ __launch_bounds__(256) void K3(
    const __bf16* __restrict__ hin, const __bf16* __restrict__ A2,
    const float* __restrict__ p2, const float* __restrict__ p1,
    const float* __restrict__ g2, const float* __restrict__ be2, const float* __restrict__ bias2,
    const float* __restrict__ gsk, const float* __restrict__ besk,
    const __bf16* __restrict__ sin_, float* __restrict__ out) {
  const int blk = ((blockIdx.x & 7) << 6) | (blockIdx.x >> 3);
  const int tx = blk & 15, ty = blk >> 4;
  const int b = blockIdx.y;
  const int y0p = ty * 8, x0p = tx * 16;
  __shared__ __attribute__((aligned(16))) __bf16 tl[2][153 * 72];
  __shared__ double redn[32];
  __shared__ float sc2[64], sh2[64], scS[64], shS[64];
  const int t = threadIdx.x;

  // prologue: reduce p2 (nrm2, cols 0-15) and p1 skip cols (nrmS, cols 16-31)
  {
    const int col = t >> 3, sub = t & 7;    // 32 cols x 8 subs
    double v = 0.0;
    if (col < 16) {
      for (int j = sub; j < 512; j += 8)
        v += (double)p2[(size_t)col * 1024 + b * 512 + j];
    } else {
      for (int j = sub; j < 512; j += 8) {
        int cc = j >> 8, rr = j & 255;
        v += (double)p1[(size_t)col * 1024 + (cc * 2 + b) * 256 + rr];
      }
    }
    v += __shfl_xor(v, 1, 64);
    v += __shfl_xor(v, 2, 64);
    v += __shfl_xor(v, 4, 64);
    if (sub == 0) redn[col] = v;
  }
  __syncthreads();
  if (t < 128) {
    int half = t >> 6, ch = t & 63, g = ch >> 3;
    if (half == 0) {
      double mean = redn[g] * INV_N;
      double var  = redn[8 + g] * INV_N - mean * mean;
      float inv = rsqrtf((float)var + EPSV);
      float s_ = inv * g2[ch];
      sc2[ch] = s_;
      sh2[ch] = be2[ch] - (float)mean * s_;
    } else {
      double mean = redn[16 + g] * INV_N;
      double var  = redn[24 + g] * INV_N - mean * mean;
      float inv = rsqrtf((float)var + EPSV);
      float s_ = inv * gsk[ch];
      scS[ch] = s_;
      shS[ch] = besk[ch] - (float)mean * s_;
    }
  }
  __syncthreads();

#pragma unroll
  for (int i = 0; i < 10; ++i) {
    int u = t + i * 256;
    if (u < 2 * 153 * 8) {
      int cs = u / 1224;
      int rr = u - cs * 1224;
      int px = rr >> 3, cg = rr & 7;
      int ly = px / 17, lx = px - ly * 17;
      int gy = y0p + ly - cs, gx = x0p + lx - cs;
      bf16x8 v;
#pragma unroll
      for (int j = 0; j < 8; ++j) v[j] = (__bf16)0.f;
      if ((unsigned)gy < 256u && (unsigned)gx < 256u) {
        bf16x8 raw = *(const bf16x8*)&hin[(((size_t)(cs * NB + b) * WD + gy) * WD + gx) * 64 + cg * 8];
#pragma unroll
        for (int j = 0; j < 8; ++j) {
          float f = fmaf((float)raw[j], sc2[cg * 8 + j], sh2[cg * 8 + j]);
          v[j] = (__bf16)fmaxf(f, 0.f);
        }
      }
      *(bf16x8*)&tl[cs][px * 72 + cg * 8] = v;
    }
  }
  __syncthreads();

  const int wv = t >> 6, lane = t & 63, ln = lane & 15, q = lane >> 4;
  const int co = wv & 1, mh = wv >> 1;
  const int q8 = q * 8;
  bf16x8 af[2][10];
#pragma unroll
  for (int m = 0; m < 2; ++m)
#pragma unroll
    for (int kk = 0; kk < 10; ++kk)
      af[m][kk] = *(const bf16x8*)&A2[(mh * 32 + m * 16 + ln) * 320 + kk * 32 + q8];

  f32x4 acc[8][2];
#pragma unroll
  for (int n = 0; n < 8; ++n)
#pragma unroll
    for (int m = 0; m < 2; ++m) acc[n][m] = (f32x4){0.f, 0.f, 0.f, 0.f};

  const __bf16* tc = tl[co];
  const __bf16* to = tl[1 - co];
#pragma unroll
  for (int n = 0; n < 8; ++n) {
    const int cpix = co ? ((n + 1) * 17 + ln + 1) : (n * 17 + ln);
    const int tb = n * 17 + ln;
    const __bf16* pc = tc + cpix * 72 + q8;
    const __bf16* p0 = to + tb * 72 + q8;
    const __bf16* p1p = to + (tb + 1) * 72 + q8;
    const __bf16* p2p = to + (tb + 17) * 72 + q8;
    const __bf16* p3 = to + (tb + 18) * 72 + q8;
    bf16x8 bb;
    bb = *(const bf16x8*)pc;         acc[n][0]=MFMA16(af[0][0],bb,acc[n][0]); acc[n][1]=MFMA16(af[1][0],bb,acc[n][1]);
    bb = *(const bf16x8*)(pc + 32);  acc[n][0]=MFMA16(af[0][1],bb,acc[n][0]); acc[n][1]=MFMA16(af[1][1],bb,acc[n][1]);
    bb = *(const bf16x8*)p0;         acc[n][0]=MFMA16(af[0][2],bb,acc[n][0]); acc[n][1]=MFMA16(af[1][2],bb,acc[n][1]);
    bb = *(const bf16x8*)(p0 + 32);  acc[n][0]=MFMA16(af[0][3],bb,acc[n][0]); acc[n][1]=MFMA16(af[1][3],bb,acc[n][1]);
    bb = *(const bf16x8*)p1p;        acc[n][0]=MFMA16(af[0][4],bb,acc[n][0]); acc[n][1]=MFMA16(af[1][4],bb,acc[n][1]);
    bb = *(const bf16x8*)(p1p + 32); acc[n][0]=MFMA16(af[0][5],bb,acc[n][0]); acc[n][1]=MFMA16(af[1][5],bb,acc[n][1]);
    bb = *(const bf16x8*)p2p;        acc[n][0]=MFMA16(af[0][6],bb,acc[n][0]); acc[n][1]=MFMA16(af[1][6],bb,acc[n][1]);
    bb = *(const bf16x8*)(p2p + 32); acc[n][0]=MFMA16(af[0][7],bb,acc[n][0]); acc[n][1]=MFMA16(af[1][7],bb,acc[n][1]);
    bb = *(const bf16x8*)p3;         acc[n][0]=MFMA16(af[0][8],bb,acc[n][0]); acc[n][1]=MFMA16(af[1][8],bb,acc[n][1]);
    bb = *(const bf16x8*)(p3 + 32);  acc[n][0]=MFMA16(af[0][9],bb,acc[n][0]); acc[n][1]=MFMA16(af[1][9],bb,acc[n][1]);
  }

  float bia[2][4], sA[2][4], sB[2][4];
#pragma unroll
  for (int m = 0; m < 2; ++m)
#pragma unroll
    for (int r = 0; r < 4; ++r) {
      int ch = mh * 32 + m * 16 + q * 4 + r;
      bia[m][r] = bias2[ch];
      sA[m][r] = scS[ch];
      sB[m][r] = shS[ch];
    }

#pragma unroll
  for (int n = 0; n < 8; ++n) {
    int gy = y0p + n;
#pragma unroll
    for (int m = 0; m < 2; ++m) {
      int ch0 = mh * 32 + m * 16 + q * 4;
      size_t sb = ((size_t)(co * NB + b) * 4096 + gy * 16 + tx) * 1024 + (mh * 8 + m * 4 + q) * 64 + ln * 4;
      bf16x4 sv = *(const bf16x4*)&sin_[sb];
      size_t ob = ((size_t)(co * NB + b) * 64 + ch0) * HW + (size_t)gy * WD + x0p + ln;
#pragma unroll
      for (int r = 0; r < 4; ++r) {
        float v = acc[n][m][r] + bia[m][r] + fmaf((float)sv[r], sA[m][r], sB[m][r]);
        out[ob + (size_t)r * HW] = v;
      }
    }
  }
}

extern "C" void kernel_launch(void* const* d_in, const int* in_sizes, int n_in,
                              void* d_out, int out_size, void* d_ws, size_t ws_size,
                              hipStream_t stream) {
  (void)in_sizes; (void)n_in; (void)out_size; (void)ws_size;
  const float* x0    = (const float*)d_in[0];
  const float* x1    = (const float*)d_in[1];
  const float* g1    = (const float*)d_in[2];
  const float* b1    = (const float*)d_in[3];
  const float* w1c   = (const float*)d_in[4];
  const float* w1k   = (const float*)d_in[5];
  const float* bias1 = (const float*)d_in[6];
  const float* g2    = (const float*)d_in[7];
  const float* b2    = (const float*)d_in[8];
  const float* w2c   = (const float*)d_in[9];
  const float* w2k   = (const float*)d_in[10];
  const float* bias2 = (const float*)d_in[11];
  const float* wsk   = (const float*)d_in[12];
  const float* bsk   = (const float*)d_in[13];
  const float* gsk   = (const float*)d_in[14];
  const float* besk  = (const float*)d_in[15];

  char* ws = (char*)d_ws;
  float*  p1 = (float*)(ws + OFF_P1);
  float*  p2 = (float*)(ws + OFF_P2);
  __bf16* A1 = (__bf16*)(ws + OFF_A1);
  __bf16* A2 = (__bf16*)(ws + OFF_A2);
  __bf16* xt = (__bf16*)(ws + OFF_XT);
  __bf16* s  = (__bf16*)(ws + OFF_S);
  __bf16* h  = (__bf16*)(ws + OFF_H);

  K1<<<dim3(1026), 256, 0, stream>>>(x0, x1, wsk, bsk, w1c, w1k, w2c, w2k, xt, s, A1, A2, p1);
  K2<<<dim3(512, 2), 256, 0, stream>>>(xt, A1, p1, g1, b1, bias1, h, p2);
  K3<<<dim3(512, 2), 256, 0, stream>>>(h, A2, p2, p1, g2, b2, bias2, gsk, besk, s, (float*)d_out);
}

// Round 11
// 266.515 us; speedup vs baseline: 1.2246x; 1.0042x over previous
//
#include <hip/hip_runtime.h>

typedef __attribute__((ext_vector_type(8))) __bf16 bf16x8;
typedef __attribute__((ext_vector_type(4))) __bf16 bf16x4;
typedef __attribute__((ext_vector_type(4))) float f32x4;

#define MFMA16(a,b,c) __builtin_amdgcn_mfma_f32_16x16x32_bf16(a,b,c,0,0,0)

static constexpr int HW = 65536;   // 256*256
static constexpr int WD = 256;
static constexpr int NB = 2;       // batch
static constexpr double INV_N = 1.0 / 1048576.0;   // 8ch*65536px*2cosets
static constexpr float EPSV = 1e-5f;

// workspace layout (bytes)
// p1 TRANSPOSED: [32 cols][1024 rows] f32  (row = (co*2+b)*256 + rowIdx)
// p2 TRANSPOSED: [16 cols][1024 rows] f32  (row = b*512 + blk)
static constexpr size_t OFF_P1  = 0;                   // 131072 B
static constexpr size_t OFF_P2  = 131072;              // 65536 B
static constexpr size_t OFF_A1  = 200704;              // 20480 bf16
static constexpr size_t OFF_A2  = OFF_A1 + 40960;
static constexpr size_t OFF_XT  = OFF_A2 + 40960;
static constexpr size_t SZ_T    = (size_t)2 * NB * HW * 64 * 2;  // 32 MiB
static constexpr size_t OFF_S   = OFF_XT + SZ_T;
static constexpr size_t OFF_H   = OFF_S + SZ_T;

// K1-only LDS tile: stride 64 + XOR chunk swizzle (conflict-free b128 r/w)
#define TL8(base, px, c) (*(const bf16x8*)&(base)[(px) * 64 + (((c)) ^ ((((px)) & 7) << 3))])

// ================ K1: weight prep + stats1 partials + skip GEMM + COALESCED NHWC transpose ================
__global__ __launch_bounds__(256, 4) void K1(
    const float* __restrict__ x0, const float* __restrict__ x1,
    const float* __restrict__ wskip, const float* __restrict__ bskip,
    const float* __restrict__ wc1, const float* __restrict__ wk1,
    const float* __restrict__ wc2, const float* __restrict__ wk2,
    __bf16* __restrict__ xt, __bf16* __restrict__ sout,
    __bf16* __restrict__ A1, __bf16* __restrict__ A2, float* __restrict__ p1) {
  const int bx = blockIdx.x;
  const int t = threadIdx.x;

  if (bx >= 1024) {            // weight-prep blocks
    const int stage = bx - 1024;
    const float* wc = stage ? wc2 : wc1;
    const float* wk = stage ? wk2 : wk1;
    __bf16* A = stage ? A2 : A1;
    for (int idx = t; idx < 64 * 320; idx += 256) {
      int o = idx / 320, k = idx - o * 320;
      float v;
      if (k < 64) v = wc[o * 64 + k];
      else v = wk[(o * 64 + (k & 63)) * 4 + ((k - 64) >> 6)];
      A[idx] = (__bf16)v;
    }
    return;
  }

  const int row = bx & 255, b = (bx >> 8) & 1, co = bx >> 9;
  const float* x = co ? x1 : x0;
  __shared__ __attribute__((aligned(16))) __bf16 tile[256 * 64];
  __shared__ float redp[256];
  __shared__ float reds[32];
  const int wv = t >> 6, lane = t & 63;
  const float* xbase = x + (size_t)b * 64 * HW + (size_t)row * WD + t;

  float gsum[8], gsq[8];
#pragma unroll
  for (int g = 0; g < 8; ++g) { gsum[g] = 0.f; gsq[g] = 0.f; }
#pragma unroll
  for (int hf = 0; hf < 2; ++hf) {
    float f[32];
#pragma unroll
    for (int k = 0; k < 32; ++k) f[k] = xbase[(size_t)(hf * 32 + k) * HW];
    __builtin_amdgcn_sched_barrier(0);   // pin: all 32 loads issued before any consume
#pragma unroll
    for (int c4 = 0; c4 < 4; ++c4) {
      const int cg = hf * 4 + c4;
      bf16x8 v;
#pragma unroll
      for (int j = 0; j < 8; ++j) {
        float xv = f[c4 * 8 + j];
        v[j] = (__bf16)xv;
        gsum[cg] += xv;
        gsq[cg] = fmaf(xv, xv, gsq[cg]);
      }
      *(bf16x8*)&tile[t * 64 + ((cg ^ (t & 7)) * 8)] = v;
    }
  }
#pragma unroll
  for (int g = 0; g < 8; ++g) {
#pragma unroll
    for (int m = 1; m < 16; m <<= 1) {
      gsum[g] += __shfl_xor(gsum[g], m, 64);
      gsq[g]  += __shfl_xor(gsq[g], m, 64);
    }
  }
  {
    const int q0 = lane >> 4;
    if ((lane & 15) == 0) {
#pragma unroll
      for (int g = 0; g < 8; ++g) {
        redp[(wv * 4 + q0) * 16 + g] = gsum[g];
        redp[(wv * 4 + q0) * 16 + 8 + g] = gsq[g];
      }
    }
  }
  __syncthreads();

  const int ln = lane & 15, q = lane >> 4;
  bf16x8 a0, a1;
#pragma unroll
  for (int j = 0; j < 8; ++j) {
    a0[j] = (__bf16)wskip[(wv * 16 + ln) * 64 + q * 8 + j];
    a1[j] = (__bf16)wskip[(wv * 16 + ln) * 64 + 32 + q * 8 + j];
  }
  float bia[4];
#pragma unroll
  for (int r = 0; r < 4; ++r) bia[r] = bskip[wv * 16 + q * 4 + r];

  float ssum = 0.f, ssq = 0.f;
  for (int n = 0; n < 16; ++n) {
    f32x4 acc = {0.f, 0.f, 0.f, 0.f};
    const int px = n * 16 + ln;
    bf16x8 b0 = TL8(tile, px, q * 8);
    bf16x8 b1 = TL8(tile, px, q * 8 + 32);
    acc = MFMA16(a0, b0, acc);
    acc = MFMA16(a1, b1, acc);
    bf16x4 sv;
#pragma unroll
    for (int r = 0; r < 4; ++r) {
      float v = acc[r] + bia[r];
      ssum += v;
      ssq = fmaf(v, v, ssq);
      sv[r] = (__bf16)v;
    }
    size_t sb = ((size_t)(co * NB + b) * 4096 + row * 16 + n) * 1024 + (wv * 4 + q) * 64 + ln * 4;
    *(bf16x4*)&sout[sb] = sv;
  }

  // coalesced xt store from LDS tile (16 B/lane contiguous)
  {
    const size_t xtrow = (((size_t)(co * NB + b) * HW) + (size_t)row * WD) * 64;
#pragma unroll
    for (int i = 0; i < 8; ++i) {
      int u = i * 256 + t;
      int px = u >> 3, chunk = u & 7;
      bf16x8 vv = *(const bf16x8*)&tile[px * 64 + ((chunk ^ (px & 7)) * 8)];
      *(bf16x8*)&xt[xtrow + (size_t)u * 8] = vv;
    }
  }

#pragma unroll
  for (int m = 1; m < 16; m <<= 1) {
    ssum += __shfl_xor(ssum, m, 64);
    ssq  += __shfl_xor(ssq, m, 64);
  }
  if ((lane & 15) == 0) {
    reds[wv * 4 + q] = ssum;
    reds[16 + wv * 4 + q] = ssq;
  }
  __syncthreads();
  if (t < 32) {
    float val;
    if (t < 16) {
      val = 0.f;
#pragma unroll
      for (int k = 0; k < 16; ++k) val += redp[k * 16 + t];
    } else {
      int kind = (t >> 3) & 1, g = t & 7;
      int wvv = g >> 1, qp = g & 1;
      val = reds[kind * 16 + wvv * 4 + qp * 2] + reds[kind * 16 + wvv * 4 + qp * 2 + 1];
    }
    // TRANSPOSED partials store: p1[col][row] -> coalesced prologue reads in K2/K3
    const int bf1 = (co * 2 + b) * 256 + row;
    p1[(size_t)t * 1024 + bf1] = val;
  }
}

// ================ K2: per-block nrm1 reduce (coalesced) + norm1+relu staging + qc_conv1 + stats2 partials ================
__global__ __launch_bounds__(256) void K2(
    const __bf16* __restrict__ xt, const __bf16* __restrict__ A1,
    const float* __restrict__ p1, const float* __restrict__ g1, const float* __restrict__ be1,
    const float* __restrict__ bias1,
    __bf16* __restrict__ h, float* __restrict__ p2) {
  // XCD swizzle: band of 64 consecutive tiles per XCD for halo L2 locality
  const int blk = ((blockIdx.x & 7) << 6) | (blockIdx.x >> 3);
  const int tx = blk & 15, ty = blk >> 4;
  const int b = blockIdx.y;
  const int y0p = ty * 8, x0p = tx * 16;
  __shared__ __attribute__((aligned(16))) __bf16 tl[2][153 * 72];
  __shared__ double redn[16];
  __shared__ float sc[64], sh[64];
  __shared__ float lst[16];
  const int t = threadIdx.x;

  // prologue: reduce p1 stats1 (16 cols x 512 rows for our b) -> nrm1
  {
    const int col = t >> 4, sub = t & 15;    // 16 cols x 16 subs
    double v = 0.0;
    for (int j = sub; j < 512; j += 16) {
      int cc = j >> 8, rr = j & 255;
      v += (double)p1[(size_t)col * 1024 + (cc * 2 + b) * 256 + rr];
    }
    v += __shfl_xor(v, 1, 64);
    v += __shfl_xor(v, 2, 64);
    v += __shfl_xor(v, 4, 64);
    v += __shfl_xor(v, 8, 64);
    if (sub == 0) redn[col] = v;
  }
  if (t < 16) lst[t] = 0.f;
  __syncthreads();
  if (t < 64) {
    int g = t >> 3;
    double mean = redn[g] * INV_N;
    double var  = redn[8 + g] * INV_N - mean * mean;
    float inv = rsqrtf((float)var + EPSV);
    float s_ = inv * g1[t];
    sc[t] = s_;
    sh[t] = be1[t] - (float)mean * s_;
  }
  __syncthreads();

  // staging: fixed 10 predicated iterations
#pragma unroll
  for (int i = 0; i < 10; ++i) {
    int u = t + i * 256;
    if (u < 2 * 153 * 8) {
      int cs = u / 1224;
      int rr = u - cs * 1224;
      int px = rr >> 3, cg = rr & 7;
      int ly = px / 17, lx = px - ly * 17;
      int gy = y0p + ly - cs, gx = x0p + lx - cs;
      bf16x8 v;
#pragma unroll
      for (int j = 0; j < 8; ++j) v[j] = (__bf16)0.f;
      if ((unsigned)gy < 256u && (unsigned)gx < 256u) {
        bf16x8 raw = *(const bf16x8*)&xt[(((size_t)(cs * NB + b) * WD + gy) * WD + gx) * 64 + cg * 8];
#pragma unroll
        for (int j = 0; j < 8; ++j) {
          float f = fmaf((float)raw[j], sc[cg * 8 + j], sh[cg * 8 + j]);
          v[j] = (__bf16)fmaxf(f, 0.f);
        }
      }
      *(bf16x8*)&tl[cs][px * 72 + cg * 8] = v;
    }
  }
  __syncthreads();

  const int wv = t >> 6, lane = t & 63, ln = lane & 15, q = lane >> 4;
  const int co = wv & 1, mh = wv >> 1;
  const int q8 = q * 8;
  bf16x8 af[2][10];
#pragma unroll
  for (int m = 0; m < 2; ++m)
#pragma unroll
    for (int kk = 0; kk < 10; ++kk)
      af[m][kk] = *(const bf16x8*)&A1[(mh * 32 + m * 16 + ln) * 320 + kk * 32 + q8];

  f32x4 acc[8][2];
#pragma unroll
  for (int n = 0; n < 8; ++n)
#pragma unroll
    for (int m = 0; m < 2; ++m) acc[n][m] = (f32x4){0.f, 0.f, 0.f, 0.f};

  const __bf16* tc = tl[co];
  const __bf16* to = tl[1 - co];
#pragma unroll
  for (int n = 0; n < 8; ++n) {
    const int cpix = co ? ((n + 1) * 17 + ln + 1) : (n * 17 + ln);
    const int tb = n * 17 + ln;
    const __bf16* pc = tc + cpix * 72 + q8;
    const __bf16* p0 = to + tb * 72 + q8;
    const __bf16* p1p = to + (tb + 1) * 72 + q8;
    const __bf16* p2p = to + (tb + 17) * 72 + q8;
    const __bf16* p3 = to + (tb + 18) * 72 + q8;
    bf16x8 bb;
    bb = *(const bf16x8*)pc;         acc[n][0]=MFMA16(af[0][0],bb,acc[n][0]); acc[n][1]=MFMA16(af[1][0],bb,acc[n][1]);
    bb = *(const bf16x8*)(pc + 32);  acc[n][0]=MFMA16(af[0][1],bb,acc[n][0]); acc[n][1]=MFMA16(af[1][1],bb,acc[n][1]);
    bb = *(const bf16x8*)p0;         acc[n][0]=MFMA16(af[0][2],bb,acc[n][0]); acc[n][1]=MFMA16(af[1][2],bb,acc[n][1]);
    bb = *(const bf16x8*)(p0 + 32);  acc[n][0]=MFMA16(af[0][3],bb,acc[n][0]); acc[n][1]=MFMA16(af[1][3],bb,acc[n][1]);
    bb = *(const bf16x8*)p1p;        acc[n][0]=MFMA16(af[0][4],bb,acc[n][0]); acc[n][1]=MFMA16(af[1][4],bb,acc[n][1]);
    bb = *(const bf16x8*)(p1p + 32); acc[n][0]=MFMA16(af[0][5],bb,acc[n][0]); acc[n][1]=MFMA16(af[1][5],bb,acc[n][1]);
    bb = *(const bf16x8*)p2p;        acc[n][0]=MFMA16(af[0][6],bb,acc[n][0]); acc[n][1]=MFMA16(af[1][6],bb,acc[n][1]);
    bb = *(const bf16x8*)(p2p + 32); acc[n][0]=MFMA16(af[0][7],bb,acc[n][0]); acc[n][1]=MFMA16(af[1][7],bb,acc[n][1]);
    bb = *(const bf16x8*)p3;         acc[n][0]=MFMA16(af[0][8],bb,acc[n][0]); acc[n][1]=MFMA16(af[1][8],bb,acc[n][1]);
    bb = *(const bf16x8*)(p3 + 32);  acc[n][0]=MFMA16(af[0][9],bb,acc[n][0]); acc[n][1]=MFMA16(af[1][9],bb,acc[n][1]);
  }

  __syncthreads();   // all waves done reading tl — safe to overwrite with h values

  float s2s[2] = {0.f, 0.f}, s2q[2] = {0.f, 0.f};
  float bia[2][4];
#pragma unroll
  for (int m = 0; m < 2; ++m)
#pragma unroll
    for (int r = 0; r < 4; ++r) bia[m][r] = bias1[mh * 32 + m * 16 + q * 4 + r];

#pragma unroll
  for (int n = 0; n < 8; ++n)
#pragma unroll
    for (int m = 0; m < 2; ++m) {
      bf16x4 hv;
#pragma unroll
      for (int r = 0; r < 4; ++r) {
        float v = acc[n][m][r] + bia[m][r];
        s2s[m] += v;
        s2q[m] = fmaf(v, v, s2q[m]);
        hv[r] = (__bf16)v;
      }
      *(bf16x4*)&tl[co][(n * 16 + ln) * 72 + mh * 32 + m * 16 + q * 4] = hv;
    }

#pragma unroll
  for (int m = 0; m < 2; ++m) {
    float a_ = s2s[m], c_ = s2q[m];
#pragma unroll
    for (int mk = 1; mk < 32; mk <<= 1) {
      a_ += __shfl_xor(a_, mk, 64);
      c_ += __shfl_xor(c_, mk, 64);
    }
    if ((lane & 31) == 0) {
      int g = mh * 4 + m * 2 + (q >> 1);
      atomicAdd(&lst[g], a_);
      atomicAdd(&lst[8 + g], c_);
    }
  }
  __syncthreads();

  // coalesced h store (NHWC), 16 B/lane
#pragma unroll
  for (int i = 0; i < 8; ++i) {
    int co2 = i >> 2;
    int idx = (i & 3) * 256 + t;
    int px = idx >> 3, chunk = idx & 7;
    int gy = y0p + (px >> 4), gx = x0p + (px & 15);
    bf16x8 vv = *(const bf16x8*)&tl[co2][px * 72 + chunk * 8];
    *(bf16x8*)&h[(((size_t)(co2 * NB + b) * WD + gy) * WD + gx) * 64 + chunk * 8] = vv;
  }

  // TRANSPOSED partials store: p2[col][b*512 + blk]
  if (t < 16) p2[(size_t)t * 1024 + b * 512 + blockIdx.x] = lst[t];
}

// ================ K3: per-block nrm2+nrmS reduce (coalesced) + norm2+relu staging + qc_conv2 + skip + fp32 out ================
__global__ __launch_bounds__(256) void K3(
    const __bf16* __restrict__ hin, const __bf16* __restrict__ A2,
    const float* __restrict__ p2, const float* __restrict__ p1,
    const float* __restrict__ g2, const float* __restrict__ be2, const float* __restrict__ bias2,
    const float* __restrict__ gsk, const float* __restrict__ besk,
    const __bf16* __restrict__ sin_, float* __restrict__ out) {
  const int blk = ((blockIdx.x & 7) << 6) | (blockIdx.x >> 3);
  const int tx = blk & 15, ty = blk >> 4;
  const int b = blockIdx.y;
  const int y0p = ty * 8, x0p = tx * 16;
  __shared__ __attribute__((aligned(16))) __bf16 tl[2][153 * 72];
  __shared__ double redn[32];
  __shared__ float sc2[64], sh2[64], scS[64], shS[64];
  const int t = threadIdx.x;

  // prologue: reduce p2 (nrm2, cols 0-15) and p1 skip cols (nrmS, cols 16-31)
  {
    const int col = t >> 3, sub = t & 7;    // 32 cols x 8 subs
    double v = 0.0;
    if (col < 16) {
      for (int j = sub; j < 512; j += 8)
        v += (double)p2[(size_t)col * 1024 + b * 512 + j];
    } else {
      for (int j = sub; j < 512; j += 8) {
        int cc = j >> 8, rr = j & 255;
        v += (double)p1[(size_t)col * 1024 + (cc * 2 + b) * 256 + rr];
      }
    }
    v += __shfl_xor(v, 1, 64);
    v += __shfl_xor(v, 2, 64);
    v += __shfl_xor(v, 4, 64);
    if (sub == 0) redn[col] = v;
  }
  __syncthreads();
  if (t < 128) {
    int half = t >> 6, ch = t & 63, g = ch >> 3;
    if (half == 0) {
      double mean = redn[g] * INV_N;
      double var  = redn[8 + g] * INV_N - mean * mean;
      float inv = rsqrtf((float)var + EPSV);
      float s_ = inv * g2[ch];
      sc2[ch] = s_;
      sh2[ch] = be2[ch] - (float)mean * s_;
    } else {
      double mean = redn[16 + g] * INV_N;
      double var  = redn[24 + g] * INV_N - mean * mean;
      float inv = rsqrtf((float)var + EPSV);
      float s_ = inv * gsk[ch];
      scS[ch] = s_;
      shS[ch] = besk[ch] - (float)mean * s_;
    }
  }
  __syncthreads();

#pragma unroll
  for (int i = 0; i < 10; ++i) {
    int u = t + i * 256;
    if (u < 2 * 153 * 8) {
      int cs = u / 1224;
      int rr = u - cs * 1224;
      int px = rr >> 3, cg = rr & 7;
      int ly = px / 17, lx = px - ly * 17;
      int gy = y0p + ly - cs, gx = x0p + lx - cs;
      bf16x8 v;
#pragma unroll
      for (int j = 0; j < 8; ++j) v[j] = (__bf16)0.f;
      if ((unsigned)gy < 256u && (unsigned)gx < 256u) {
        bf16x8 raw = *(const bf16x8*)&hin[(((size_t)(cs * NB + b) * WD + gy) * WD + gx) * 64 + cg * 8];
#pragma unroll
        for (int j = 0; j < 8; ++j) {
          float f = fmaf((float)raw[j], sc2[cg * 8 + j], sh2[cg * 8 + j]);
          v[j] = (__bf16)fmaxf(f, 0.f);
        }
      }
      *(bf16x8*)&tl[cs][px * 72 + cg * 8] = v;
    }
  }
  __syncthreads();

  const int wv = t >> 6, lane = t & 63, ln = lane & 15, q = lane >> 4;
  const int co = wv & 1, mh = wv >> 1;
  const int q8 = q * 8;
  bf16x8 af[2][10];
#pragma unroll
  for (int m = 0; m < 2; ++m)
#pragma unroll
    for (int kk = 0; kk < 10; ++kk)
      af[m][kk] = *(const bf16x8*)&A2[(mh * 32 + m * 16 + ln) * 320 + kk * 32 + q8];

  f32x4 acc[8][2];
#pragma unroll
  for (int n = 0; n < 8; ++n)
#pragma unroll
    for (int m = 0; m < 2; ++m) acc[n][m] = (f32x4){0.f, 0.f, 0.f, 0.f};

  const __bf16* tc = tl[co];
  const __bf16* to = tl[1 - co];
#pragma unroll
  for (int n = 0; n < 8; ++n) {
    const int cpix = co ? ((n + 1) * 17 + ln + 1) : (n * 17 + ln);
    const int tb = n * 17 + ln;
    const __bf16* pc = tc + cpix * 72 + q8;
    const __bf16* p0 = to + tb * 72 + q8;
    const __bf16* p1p = to + (tb + 1) * 72 + q8;
    const __bf16* p2p = to + (tb + 17) * 72 + q8;
    const __bf16* p3 = to + (tb + 18) * 72 + q8;
    bf16x8 bb;
    bb = *(const bf16x8*)pc;         acc[n][0]=MFMA16(af[0][0],bb,acc[n][0]); acc[n][1]=MFMA16(af[1][0],bb,acc[n][1]);
    bb = *(const bf16x8*)(pc + 32);  acc[n][0]=MFMA16(af[0][1],bb,acc[n][0]); acc[n][1]=MFMA16(af[1][1],bb,acc[n][1]);
    bb = *(const bf16x8*)p0;         acc[n][0]=MFMA16(af[0][2],bb,acc[n][0]); acc[n][1]=MFMA16(af[1][2],bb,acc[n][1]);
    bb = *(const bf16x8*)(p0 + 32);  acc[n][0]=MFMA16(af[0][3],bb,acc[n][0]); acc[n][1]=MFMA16(af[1][3],bb,acc[n][1]);
    bb = *(const bf16x8*)p1p;        acc[n][0]=MFMA16(af[0][4],bb,acc[n][0]); acc[n][1]=MFMA16(af[1][4],bb,acc[n][1]);
    bb = *(const bf16x8*)(p1p + 32); acc[n][0]=MFMA16(af[0][5],bb,acc[n][0]); acc[n][1]=MFMA16(af[1][5],bb,acc[n][1]);
    bb = *(const bf16x8*)p2p;        acc[n][0]=MFMA16(af[0][6],bb,acc[n][0]); acc[n][1]=MFMA16(af[1][6],bb,acc[n][1]);
    bb = *(const bf16x8*)(p2p + 32); acc[n][0]=MFMA16(af[0][7],bb,acc[n][0]); acc[n][1]=MFMA16(af[1][7],bb,acc[n][1]);
    bb = *(const bf16x8*)p3;         acc[n][0]=MFMA16(af[0][8],bb,acc[n][0]); acc[n][1]=MFMA16(af[1][8],bb,acc[n][1]);
    bb = *(const bf16x8*)(p3 + 32);  acc[n][0]=MFMA16(af[0][9],bb,acc[n][0]); acc[n][1]=MFMA16(af[1][9],bb,acc[n][1]);
  }

  float bia[2][4], sA[2][4], sB[2][4];
#pragma unroll
  for (int m = 0; m < 2; ++m)
#pragma unroll
    for (int r = 0; r < 4; ++r) {
      int ch = mh * 32 + m * 16 + q * 4 + r;
      bia[m][r] = bias2[ch];
      sA[m][r] = scS[ch];
      sB[m][r] = shS[ch];
    }

#pragma unroll
  for (int n = 0; n < 8; ++n) {
    int gy = y0p + n;
#pragma unroll
    for (int m = 0; m < 2; ++m) {
      int ch0 = mh * 32 + m * 16 + q * 4;
      size_t sb = ((size_t)(co * NB + b) * 4096 + gy * 16 + tx) * 1024 + (mh * 8 + m * 4 + q) * 64 + ln * 4;
      bf16x4 sv = *(const bf16x4*)&sin_[sb];
      size_t ob = ((size_t)(co * NB + b) * 64 + ch0) * HW + (size_t)gy * WD + x0p + ln;
#pragma unroll
      for (int r = 0; r < 4; ++r) {
        float v = acc[n][m][r] + bia[m][r] + fmaf((float)sv[r], sA[m][r], sB[m][r]);
        out[ob + (size_t)r * HW] = v;
      }
    }
  }
}

extern "C" void kernel_launch(void* const* d_in, const int* in_sizes, int n_in,
                              void* d_out, int out_size, void* d_ws, size_t ws_size,
                              hipStream_t stream) {
  (void)in_sizes; (void)n_in; (void)out_size; (void)ws_size;
  const float* x0    = (const float*)d_in[0];
  const float* x1    = (const float*)d_in[1];
  const float* g1    = (const float*)d_in[2];
  const float* b1    = (const float*)d_in[3];
  const float* w1c   = (const float*)d_in[4];
  const float* w1k   = (const float*)d_in[5];
  const float* bias1 = (const float*)d_in[6];
  const float* g2    = (const float*)d_in[7];
  const float* b2    = (const float*)d_in[8];
  const float* w2c   = (const float*)d_in[9];
  const float* w2k   = (const float*)d_in[10];
  const float* bias2 = (const float*)d_in[11];
  const float* wsk   = (const float*)d_in[12];
  const float* bsk   = (const float*)d_in[13];
  const float* gsk   = (const float*)d_in[14];
  const float* besk  = (const float*)d_in[15];

  char* ws = (char*)d_ws;
  float*  p1 = (float*)(ws + OFF_P1);
  float*  p2 = (float*)(ws + OFF_P2);
  __bf16* A1 = (__bf16*)(ws + OFF_A1);
  __bf16* A2 = (__bf16*)(ws + OFF_A2);
  __bf16* xt = (__bf16*)(ws + OFF_XT);
  __bf16* s  = (__bf16*)(ws + OFF_S);
  __bf16* h  = (__bf16*)(ws + OFF_H);

  K1<<<dim3(1026), 256, 0, stream>>>(x0, x1, wsk, bsk, w1c, w1k, w2c, w2k, xt, s, A1, A2, p1);
  K2<<<dim3(512, 2), 256, 0, stream>>>(xt, A1, p1, g1, b1, bias1, h, p2);
  K3<<<dim3(512, 2), 256, 0, stream>>>(h, A2, p2, p1, g2, b2, bias2, gsk, besk, s, (float*)d_out);
}